// Round 1
// baseline (3523.524 us; speedup 1.0000x reference)
//
#include <hip/hip_runtime.h>

// Problem constants (fixed by the reference)
constexpr int NN   = 100000;   // nodes
constexpr int EE   = 1600000;  // edges
constexpr int DIM  = 64;
constexpr int HH   = 4;        // heads
constexpr int CC   = 16;       // channels / head
constexpr int LL   = 3;        // layers
constexpr int GG   = 16;       // graphs
constexpr int NCLS = 2;
constexpr float SLOPE_ATT = 0.2f;
constexpr float SLOPE_ACT = 0.01f;
constexpr float EPS = 1e-5f;

// ---- monotonic float<->uint mapping for atomicMax on floats ----
__device__ __forceinline__ unsigned fmap(float f) {
    unsigned b = __float_as_uint(f);
    return b ^ ((unsigned)((int)b >> 31) | 0x80000000u);
}
__device__ __forceinline__ float funmap(unsigned u) {
    unsigned b = (u & 0x80000000u) ? (u ^ 0x80000000u) : ~u;
    return __uint_as_float(b);
}

// ---- pool of x0 + node counts per graph ----
__global__ __launch_bounds__(256) void k_pool0(const float* __restrict__ x,
                                               const int* __restrict__ batch,
                                               float* __restrict__ pool0,
                                               float* __restrict__ cnt) {
    __shared__ float sp[GG * DIM];
    __shared__ float sc[GG];
    for (int i = threadIdx.x; i < GG * DIM; i += blockDim.x) sp[i] = 0.f;
    if (threadIdx.x < GG) sc[threadIdx.x] = 0.f;
    __syncthreads();
    const int total = NN * DIM;
    const int stride = gridDim.x * blockDim.x;
    for (int idx = blockIdx.x * blockDim.x + threadIdx.x; idx < total; idx += stride) {
        int n = idx >> 6, j = idx & 63;
        int g = batch[n];
        atomicAdd(&sp[g * DIM + j], x[idx]);
        if (j == 0) atomicAdd(&sc[g], 1.f);
    }
    __syncthreads();
    for (int i = threadIdx.x; i < GG * DIM; i += blockDim.x)
        if (sp[i] != 0.f) atomicAdd(&pool0[i], sp[i]);
    if (threadIdx.x < GG && sc[threadIdx.x] != 0.f) atomicAdd(&cnt[threadIdx.x], sc[threadIdx.x]);
}

// ---- h = x @ W  (per-row),  e_src/e_dst per-node attention logits fused ----
__global__ __launch_bounds__(256) void k_gemm(const float* __restrict__ xin,
                                              const float* __restrict__ Wl,
                                              const float* __restrict__ asrc,
                                              const float* __restrict__ adst,
                                              float* __restrict__ h,
                                              float* __restrict__ es,
                                              float* __restrict__ ed) {
    __shared__ float Ws[DIM][DIM];   // 16 KB
    __shared__ float xs[4][DIM];
    const int tid = threadIdx.x;
    for (int i = tid; i < DIM * DIM; i += 256) Ws[i >> 6][i & 63] = Wl[i];
    const int r = tid >> 6, j = tid & 63;
    const int n = blockIdx.x * 4 + r;
    xs[r][j] = (n < NN) ? xin[n * DIM + j] : 0.f;
    __syncthreads();
    if (n < NN) {
        float acc = 0.f;
#pragma unroll
        for (int k = 0; k < DIM; ++k) acc = fmaf(xs[r][k], Ws[k][j], acc);
        h[n * DIM + j] = acc;
        const int hh = j >> 4, c = j & 15;
        float ps = acc * asrc[hh * CC + c];
        float pd = acc * adst[hh * CC + c];
#pragma unroll
        for (int o = 8; o >= 1; o >>= 1) {
            ps += __shfl_xor(ps, o, 16);
            pd += __shfl_xor(pd, o, 16);
        }
        if (c == 0) { es[n * HH + hh] = ps; ed[n * HH + hh] = pd; }
    }
}

// ---- segment max of attention logits over dst ----
__global__ __launch_bounds__(256) void k_edge_max(const int* __restrict__ ei,
                                                  const float* __restrict__ es,
                                                  const float* __restrict__ ed,
                                                  unsigned* __restrict__ amax) {
    int e = blockIdx.x * blockDim.x + threadIdx.x;
    if (e >= EE) return;
    int s = ei[e], d = ei[EE + e];
    float4 a = *(const float4*)(es + s * 4);
    float4 b = *(const float4*)(ed + d * 4);
    float v[4] = {a.x + b.x, a.y + b.y, a.z + b.z, a.w + b.w};
#pragma unroll
    for (int hh = 0; hh < 4; ++hh) {
        float t = v[hh] > 0.f ? v[hh] : SLOPE_ATT * v[hh];
        atomicMax(&amax[d * 4 + hh], fmap(t));
    }
}

// ---- segment sum of exp(alpha - amax) over dst ----
__global__ __launch_bounds__(256) void k_edge_sum(const int* __restrict__ ei,
                                                  const float* __restrict__ es,
                                                  const float* __restrict__ ed,
                                                  const unsigned* __restrict__ amax,
                                                  float* __restrict__ den) {
    int e = blockIdx.x * blockDim.x + threadIdx.x;
    if (e >= EE) return;
    int s = ei[e], d = ei[EE + e];
    float4 a = *(const float4*)(es + s * 4);
    float4 b = *(const float4*)(ed + d * 4);
    float v[4] = {a.x + b.x, a.y + b.y, a.z + b.z, a.w + b.w};
#pragma unroll
    for (int hh = 0; hh < 4; ++hh) {
        float t = v[hh] > 0.f ? v[hh] : SLOPE_ATT * v[hh];
        float m = funmap(amax[d * 4 + hh]);
        atomicAdd(&den[d * 4 + hh], expf(t - m));
    }
}

// ---- weighted message scatter: one wave per edge, lane = channel ----
__global__ __launch_bounds__(256) void k_scatter(const int* __restrict__ ei,
                                                 const float* __restrict__ es,
                                                 const float* __restrict__ ed,
                                                 const unsigned* __restrict__ amax,
                                                 const float* __restrict__ den,
                                                 const float* __restrict__ h,
                                                 float* __restrict__ agg) {
    int idx = blockIdx.x * 256 + threadIdx.x;      // < EE*64 = 102.4M
    int e = idx >> 6, j = idx & 63, hh = j >> 4;
    int s = ei[e], d = ei[EE + e];
    float a = es[s * 4 + hh] + ed[d * 4 + hh];
    a = a > 0.f ? a : SLOPE_ATT * a;
    float m = funmap(amax[d * 4 + hh]);
    float ex = expf(a - m);
    float att = ex / (den[d * 4 + hh] + 1e-16f);
    float hv = h[s * 64 + j];
    atomicAdd(&agg[d * 64 + j], hv * att);
}

// ---- BatchNorm statistics (sum, sumsq per channel), f64 accumulators ----
__global__ __launch_bounds__(256) void k_bn_reduce(const float* __restrict__ agg,
                                                   const float* __restrict__ bias,
                                                   double* __restrict__ bnsum) {
    const int j = threadIdx.x & 63, r = threadIdx.x >> 6;
    const float bj = bias[j];
    double ds = 0.0, ds2 = 0.0;
    const int total = NN * 64;
    const int stride = gridDim.x * blockDim.x;
    for (int idx = blockIdx.x * blockDim.x + threadIdx.x; idx < total; idx += stride) {
        float v = agg[idx] + bj;
        ds += v;
        ds2 += (double)v * v;
    }
    __shared__ double sh[2][4][64];
    sh[0][r][j] = ds;
    sh[1][r][j] = ds2;
    __syncthreads();
    if (r == 0) {
        double t1 = sh[0][0][j] + sh[0][1][j] + sh[0][2][j] + sh[0][3][j];
        double t2 = sh[1][0][j] + sh[1][1][j] + sh[1][2][j] + sh[1][3][j];
        atomicAdd(&bnsum[j], t1);
        atomicAdd(&bnsum[64 + j], t2);
    }
}

__global__ void k_bn_final(const double* __restrict__ bnsum,
                           const float* __restrict__ gamma,
                           const float* __restrict__ beta,
                           float* __restrict__ ss) {
    int j = threadIdx.x;
    if (j < 64) {
        double mean = bnsum[j] / (double)NN;
        double var = bnsum[64 + j] / (double)NN - mean * mean;
        float sc = (float)(1.0 / sqrt(var + (double)EPS)) * gamma[j];
        ss[j] = sc;
        ss[64 + j] = beta[j] - (float)mean * sc;
    }
}

// ---- norm + GraphSizeNorm + LeakyReLU + pool + residual ----
__global__ __launch_bounds__(256) void k_norm_act(const float* __restrict__ agg,
                                                  const float* __restrict__ bias,
                                                  const float* __restrict__ ss,
                                                  const int* __restrict__ batch,
                                                  const float* __restrict__ cnt,
                                                  float* __restrict__ xcur,
                                                  float* __restrict__ pool) {
    __shared__ float sp[GG * 64];
    for (int i = threadIdx.x; i < GG * 64; i += blockDim.x) sp[i] = 0.f;
    __syncthreads();
    const int j = threadIdx.x & 63;
    const float bj = bias[j], sc = ss[j], shf = ss[64 + j];
    const int total = NN * 64;
    const int stride = gridDim.x * blockDim.x;
    for (int idx = blockIdx.x * blockDim.x + threadIdx.x; idx < total; idx += stride) {
        int n = idx >> 6;
        int g = batch[n];
        float v = (agg[idx] + bj) * sc + shf;
        v *= rsqrtf(cnt[g]);
        v = v > 0.f ? v : SLOPE_ACT * v;
        atomicAdd(&sp[g * 64 + j], v);
        xcur[idx] += v;
    }
    __syncthreads();
    for (int i = threadIdx.x; i < GG * 64; i += blockDim.x)
        if (sp[i] != 0.f) atomicAdd(&pool[i], sp[i]);
}

// ---- readout head: concat-pool GEMM + softmax + argmax ----
__global__ void k_head(const float* __restrict__ pools,
                       const float* __restrict__ cnt,
                       const float* __restrict__ Wr,
                       const float* __restrict__ br,
                       float* __restrict__ out) {
    __shared__ float risk[GG * NCLS];
    int t = threadIdx.x;
    if (t < GG * NCLS) {
        int g = t / NCLS, c = t % NCLS;
        float acc = br[c];
        float icnt = 1.f / cnt[g];
        for (int k = 0; k < (LL + 1) * DIM; ++k) {
            int l = k >> 6, j = k & 63;
            float xc = pools[(l * GG + g) * 64 + j] * icnt;
            acc += xc * Wr[k * NCLS + c];
        }
        risk[t] = acc;
        out[t] = acc;
    }
    __syncthreads();
    if (t < GG) {
        float r0 = risk[t * 2], r1 = risk[t * 2 + 1];
        float m = fmaxf(r0, r1);
        float e0 = expf(r0 - m), e1 = expf(r1 - m);
        float s = e0 + e1;
        out[GG * NCLS + t * 2] = e0 / s;
        out[GG * NCLS + t * 2 + 1] = e1 / s;
        out[2 * GG * NCLS + t] = (r1 > r0) ? 1.f : 0.f;   // argmax, first-max on ties
    }
}

extern "C" void kernel_launch(void* const* d_in, const int* in_sizes, int n_in,
                              void* d_out, int out_size, void* d_ws, size_t ws_size,
                              hipStream_t stream) {
    const float* x     = (const float*)d_in[0];
    const int*   ei    = (const int*)d_in[1];
    const int*   batch = (const int*)d_in[2];
    // d_in[3] = n_graphs (known at compile time)
    const float* W     = (const float*)d_in[4];
    const float* asrc  = (const float*)d_in[5];
    const float* adst  = (const float*)d_in[6];
    const float* bias  = (const float*)d_in[7];
    const float* gamma = (const float*)d_in[8];
    const float* beta  = (const float*)d_in[9];
    const float* Wr    = (const float*)d_in[10];
    const float* br    = (const float*)d_in[11];
    float* out = (float*)d_out;

    char* ws = (char*)d_ws;
    size_t off = 0;
    auto alloc = [&](size_t bytes) {
        void* p = ws + off;
        off += (bytes + 255) & ~(size_t)255;
        return p;
    };
    float*    xcur  = (float*)alloc((size_t)NN * 64 * 4);
    float*    h     = (float*)alloc((size_t)NN * 64 * 4);
    float*    agg   = (float*)alloc((size_t)NN * 64 * 4);
    float*    es    = (float*)alloc((size_t)NN * 4 * 4);
    float*    ed    = (float*)alloc((size_t)NN * 4 * 4);
    unsigned* amax  = (unsigned*)alloc((size_t)NN * 4 * 4);
    float*    den   = (float*)alloc((size_t)NN * 4 * 4);
    double*   bnsum = (double*)alloc(128 * 8);
    float*    ss    = (float*)alloc(128 * 4);
    float*    pools = (float*)alloc((size_t)(LL + 1) * GG * 64 * 4);
    float*    cnt   = (float*)alloc((size_t)GG * 4);
    (void)ws_size; (void)in_sizes; (void)n_in; (void)out_size;

    // running x and global accumulators
    hipMemcpyAsync(xcur, x, (size_t)NN * 64 * 4, hipMemcpyDeviceToDevice, stream);
    hipMemsetAsync(pools, 0, (size_t)(LL + 1) * GG * 64 * 4, stream);
    hipMemsetAsync(cnt, 0, (size_t)GG * 4, stream);

    k_pool0<<<2048, 256, 0, stream>>>(x, batch, pools, cnt);

    for (int l = 0; l < LL; ++l) {
        hipMemsetAsync(amax, 0, (size_t)NN * 4 * 4, stream);   // 0 == fmap(-inf) lower bound
        hipMemsetAsync(den, 0, (size_t)NN * 4 * 4, stream);
        hipMemsetAsync(agg, 0, (size_t)NN * 64 * 4, stream);
        hipMemsetAsync(bnsum, 0, 128 * 8, stream);

        k_gemm<<<NN / 4, 256, 0, stream>>>(xcur, W + l * DIM * DIM,
                                           asrc + l * HH * CC, adst + l * HH * CC,
                                           h, es, ed);
        k_edge_max<<<(EE + 255) / 256, 256, 0, stream>>>(ei, es, ed, amax);
        k_edge_sum<<<(EE + 255) / 256, 256, 0, stream>>>(ei, es, ed, amax, den);
        k_scatter<<<(EE * 64) / 256, 256, 0, stream>>>(ei, es, ed, amax, den, h, agg);
        k_bn_reduce<<<1024, 256, 0, stream>>>(agg, bias + l * DIM, bnsum);
        k_bn_final<<<1, 64, 0, stream>>>(bnsum, gamma + l * DIM, beta + l * DIM, ss);
        k_norm_act<<<2048, 256, 0, stream>>>(agg, bias + l * DIM, ss, batch, cnt,
                                             xcur, pools + (size_t)(l + 1) * GG * 64);
    }

    k_head<<<1, 64, 0, stream>>>(pools, cnt, Wr, br, out);
}

// Round 2
// 1144.909 us; speedup vs baseline: 3.0776x; 3.0776x over previous
//
#include <hip/hip_runtime.h>

// Problem constants (fixed by the reference)
constexpr int NN   = 100000;   // nodes
constexpr int EE   = 1600000;  // edges
constexpr int DIM  = 64;
constexpr int HH   = 4;        // heads
constexpr int CC   = 16;       // channels / head
constexpr int LL   = 3;        // layers
constexpr int GG   = 16;       // graphs
constexpr int NCLS = 2;
constexpr float SLOPE_ATT = 0.2f;
constexpr float SLOPE_ACT = 0.01f;
constexpr float EPS = 1e-5f;

constexpr int SCAN_CHUNK = 1024;
constexpr int NSCAN = (NN + SCAN_CHUNK - 1) / SCAN_CHUNK;   // 98

// ---- pool of x0 + node counts per graph ----
__global__ __launch_bounds__(256) void k_pool0(const float* __restrict__ x,
                                               const int* __restrict__ batch,
                                               float* __restrict__ pool0,
                                               float* __restrict__ cnt) {
    __shared__ float sp[GG * DIM];
    __shared__ float sc[GG];
    for (int i = threadIdx.x; i < GG * DIM; i += blockDim.x) sp[i] = 0.f;
    if (threadIdx.x < GG) sc[threadIdx.x] = 0.f;
    __syncthreads();
    const int total = NN * DIM;
    const int stride = gridDim.x * blockDim.x;
    for (int idx = blockIdx.x * blockDim.x + threadIdx.x; idx < total; idx += stride) {
        int n = idx >> 6, j = idx & 63;
        int g = batch[n];
        atomicAdd(&sp[g * DIM + j], x[idx]);
        if (j == 0) atomicAdd(&sc[g], 1.f);
    }
    __syncthreads();
    for (int i = threadIdx.x; i < GG * DIM; i += blockDim.x)
        if (sp[i] != 0.f) atomicAdd(&pool0[i], sp[i]);
    if (threadIdx.x < GG && sc[threadIdx.x] != 0.f) atomicAdd(&cnt[threadIdx.x], sc[threadIdx.x]);
}

// ---- CSR build: histogram of dst ----
__global__ __launch_bounds__(256) void k_hist(const int* __restrict__ ei,
                                              int* __restrict__ deg) {
    int e = blockIdx.x * 256 + threadIdx.x;
    if (e < EE) atomicAdd(&deg[ei[EE + e]], 1);
}

// ---- scan step 1: per-chunk exclusive scan + chunk totals ----
__global__ __launch_bounds__(256) void k_scan1(const int* __restrict__ deg,
                                               int* __restrict__ excl,
                                               int* __restrict__ bsum) {
    __shared__ int sh[256];
    const int b = blockIdx.x, t = threadIdx.x;
    const int i0 = b * SCAN_CHUNK + t * 4;
    int v[4];
#pragma unroll
    for (int i = 0; i < 4; ++i) v[i] = (i0 + i < NN) ? deg[i0 + i] : 0;
    int tsum = v[0] + v[1] + v[2] + v[3];
    sh[t] = tsum;
    __syncthreads();
    for (int o = 1; o < 256; o <<= 1) {
        int x = (t >= o) ? sh[t - o] : 0;
        __syncthreads();
        sh[t] += x;
        __syncthreads();
    }
    if (t == 255) bsum[b] = sh[255];
    int run = sh[t] - tsum;    // exclusive offset of this thread within chunk
#pragma unroll
    for (int i = 0; i < 4; ++i) {
        if (i0 + i < NN) excl[i0 + i] = run;
        run += v[i];
    }
}

// ---- scan step 2: exclusive scan of chunk totals (1 block) ----
__global__ void k_scan2(const int* __restrict__ bsum, int* __restrict__ bsum_sc) {
    __shared__ int sh[128];
    const int t = threadIdx.x;
    const int own = (t < NSCAN) ? bsum[t] : 0;
    sh[t] = own;
    __syncthreads();
    for (int o = 1; o < 128; o <<= 1) {
        int x = (t >= o) ? sh[t - o] : 0;
        __syncthreads();
        sh[t] += x;
        __syncthreads();
    }
    if (t < NSCAN) bsum_sc[t] = sh[t] - own;
}

// ---- scan step 3: add chunk offsets in place, set sentinel ----
__global__ __launch_bounds__(256) void k_scan3(int* __restrict__ row_start,
                                               const int* __restrict__ bsum_sc) {
    int i = blockIdx.x * 256 + threadIdx.x;
    if (i < NN) row_start[i] = row_start[i] + bsum_sc[i / SCAN_CHUNK];
    if (i == 0) row_start[NN] = EE;
}

// ---- CSR fill: place src of each edge into its dst segment ----
__global__ __launch_bounds__(256) void k_fill(const int* __restrict__ ei,
                                              int* __restrict__ cursor,
                                              int* __restrict__ ssrc) {
    int e = blockIdx.x * 256 + threadIdx.x;
    if (e >= EE) return;
    int d = ei[EE + e], s = ei[e];
    int pos = atomicAdd(&cursor[d], 1);
    ssrc[pos] = s;
}

// ---- h = x @ W (16 rows/block), fused per-node attention logits ----
__global__ __launch_bounds__(256) void k_gemm(const float* __restrict__ xin,
                                              const float* __restrict__ Wl,
                                              const float* __restrict__ asrc,
                                              const float* __restrict__ adst,
                                              float* __restrict__ h,
                                              float* __restrict__ es,
                                              float* __restrict__ ed) {
    __shared__ float Ws[DIM][DIM];   // 16 KB
    __shared__ float xs[16][DIM];    // 4 KB
    const int tid = threadIdx.x;
    const float4* W4 = (const float4*)Wl;
    float4* Ws4 = (float4*)Ws;
#pragma unroll
    for (int i = 0; i < 4; ++i) Ws4[tid + 256 * i] = W4[tid + 256 * i];
    const float4* X4 = (const float4*)(xin + (size_t)blockIdx.x * 16 * DIM);
    ((float4*)xs)[tid] = X4[tid];
    __syncthreads();
    const int j = tid & 63, slot = tid >> 6;
    float acc[4] = {0.f, 0.f, 0.f, 0.f};
#pragma unroll
    for (int k = 0; k < DIM; ++k) {
        float w = Ws[k][j];
        acc[0] = fmaf(xs[slot][k],      w, acc[0]);
        acc[1] = fmaf(xs[slot + 4][k],  w, acc[1]);
        acc[2] = fmaf(xs[slot + 8][k],  w, acc[2]);
        acc[3] = fmaf(xs[slot + 12][k], w, acc[3]);
    }
    const int hh = j >> 4, c = j & 15;
    const float as = asrc[hh * CC + c], ad = adst[hh * CC + c];
#pragma unroll
    for (int i = 0; i < 4; ++i) {
        int n = blockIdx.x * 16 + slot + 4 * i;
        h[n * DIM + j] = acc[i];
        float ps = acc[i] * as, pd = acc[i] * ad;
#pragma unroll
        for (int o = 8; o >= 1; o >>= 1) {
            ps += __shfl_xor(ps, o, 16);
            pd += __shfl_xor(pd, o, 16);
        }
        if (c == 0) { es[n * HH + hh] = ps; ed[n * HH + hh] = pd; }
    }
}

// ---- fused GAT aggregation: one wave per dst node, lane = channel ----
// pass1: per-head max over in-edges; pass2: acc = sum ex*h[src], den = sum ex
__global__ __launch_bounds__(256) void k_gat_agg(const int* __restrict__ row_start,
                                                 const int* __restrict__ ssrc,
                                                 const float* __restrict__ es,
                                                 const float* __restrict__ ed,
                                                 const float* __restrict__ h,
                                                 float* __restrict__ agg) {
    __shared__ int    sbuf[4][64];
    __shared__ float4 exbuf[4][64];
    const int wid = threadIdx.x >> 6;
    const int j   = threadIdx.x & 63;
    const int hh  = j >> 4;
    const int n   = blockIdx.x * 4 + wid;          // grid = NN/4 exact
    const int base = row_start[n];
    const int deg  = row_start[n + 1] - base;
    const float4 edv = *(const float4*)(ed + n * 4);

    // pass 1: per-head max (lane-parallel over edges)
    float4 mx = make_float4(-INFINITY, -INFINITY, -INFINITY, -INFINITY);
    for (int c0 = 0; c0 < deg; c0 += 64) {
        int cn = min(64, deg - c0);
        if (j < cn) {
            int s = ssrc[base + c0 + j];
            float4 ev = *(const float4*)(es + s * 4);
            float a0 = ev.x + edv.x; a0 = a0 > 0.f ? a0 : SLOPE_ATT * a0;
            float a1 = ev.y + edv.y; a1 = a1 > 0.f ? a1 : SLOPE_ATT * a1;
            float a2 = ev.z + edv.z; a2 = a2 > 0.f ? a2 : SLOPE_ATT * a2;
            float a3 = ev.w + edv.w; a3 = a3 > 0.f ? a3 : SLOPE_ATT * a3;
            mx.x = fmaxf(mx.x, a0); mx.y = fmaxf(mx.y, a1);
            mx.z = fmaxf(mx.z, a2); mx.w = fmaxf(mx.w, a3);
        }
    }
#pragma unroll
    for (int o = 1; o < 64; o <<= 1) {
        mx.x = fmaxf(mx.x, __shfl_xor(mx.x, o));
        mx.y = fmaxf(mx.y, __shfl_xor(mx.y, o));
        mx.z = fmaxf(mx.z, __shfl_xor(mx.z, o));
        mx.w = fmaxf(mx.w, __shfl_xor(mx.w, o));
    }

    // pass 2: exp weights + weighted gather of h rows
    float acc = 0.f;
    float4 den = make_float4(0.f, 0.f, 0.f, 0.f);
    for (int c0 = 0; c0 < deg; c0 += 64) {
        int cn = min(64, deg - c0);
        float4 ex = make_float4(0.f, 0.f, 0.f, 0.f);
        int s = 0;
        if (j < cn) {
            s = ssrc[base + c0 + j];
            float4 ev = *(const float4*)(es + s * 4);
            float a0 = ev.x + edv.x; a0 = a0 > 0.f ? a0 : SLOPE_ATT * a0;
            float a1 = ev.y + edv.y; a1 = a1 > 0.f ? a1 : SLOPE_ATT * a1;
            float a2 = ev.z + edv.z; a2 = a2 > 0.f ? a2 : SLOPE_ATT * a2;
            float a3 = ev.w + edv.w; a3 = a3 > 0.f ? a3 : SLOPE_ATT * a3;
            ex.x = __expf(a0 - mx.x); ex.y = __expf(a1 - mx.y);
            ex.z = __expf(a2 - mx.z); ex.w = __expf(a3 - mx.w);
        }
        den.x += ex.x; den.y += ex.y; den.z += ex.z; den.w += ex.w;
        sbuf[wid][j] = s;
        exbuf[wid][j] = ex;
        for (int i = 0; i < cn; ++i) {
            int si = sbuf[wid][i];
            const float* exf = (const float*)&exbuf[wid][i];
            float exh = exf[hh];
            acc = fmaf(exh, h[si * 64 + j], acc);
        }
    }
#pragma unroll
    for (int o = 1; o < 64; o <<= 1) {
        den.x += __shfl_xor(den.x, o);
        den.y += __shfl_xor(den.y, o);
        den.z += __shfl_xor(den.z, o);
        den.w += __shfl_xor(den.w, o);
    }
    const float* denf = (const float*)&den;
    agg[n * 64 + j] = acc / (denf[hh] + 1e-16f);
}

// ---- BatchNorm statistics (sum, sumsq per channel), f64 accumulators ----
__global__ __launch_bounds__(256) void k_bn_reduce(const float* __restrict__ agg,
                                                   const float* __restrict__ bias,
                                                   double* __restrict__ bnsum) {
    const int j = threadIdx.x & 63, r = threadIdx.x >> 6;
    const float bj = bias[j];
    double ds = 0.0, ds2 = 0.0;
    const int total = NN * 64;
    const int stride = gridDim.x * blockDim.x;
    for (int idx = blockIdx.x * blockDim.x + threadIdx.x; idx < total; idx += stride) {
        float v = agg[idx] + bj;
        ds += v;
        ds2 += (double)v * v;
    }
    __shared__ double sh[2][4][64];
    sh[0][r][j] = ds;
    sh[1][r][j] = ds2;
    __syncthreads();
    if (r == 0) {
        double t1 = sh[0][0][j] + sh[0][1][j] + sh[0][2][j] + sh[0][3][j];
        double t2 = sh[1][0][j] + sh[1][1][j] + sh[1][2][j] + sh[1][3][j];
        atomicAdd(&bnsum[j], t1);
        atomicAdd(&bnsum[64 + j], t2);
    }
}

__global__ void k_bn_final(const double* __restrict__ bnsum,
                           const float* __restrict__ gamma,
                           const float* __restrict__ beta,
                           float* __restrict__ ss) {
    int j = threadIdx.x;
    if (j < 64) {
        double mean = bnsum[j] / (double)NN;
        double var = bnsum[64 + j] / (double)NN - mean * mean;
        float sc = (float)(1.0 / sqrt(var + (double)EPS)) * gamma[j];
        ss[j] = sc;
        ss[64 + j] = beta[j] - (float)mean * sc;
    }
}

// ---- norm + GraphSizeNorm + LeakyReLU + pool + residual ----
__global__ __launch_bounds__(256) void k_norm_act(const float* __restrict__ agg,
                                                  const float* __restrict__ bias,
                                                  const float* __restrict__ ss,
                                                  const int* __restrict__ batch,
                                                  const float* __restrict__ cnt,
                                                  float* __restrict__ xcur,
                                                  float* __restrict__ pool) {
    __shared__ float sp[GG * 64];
    for (int i = threadIdx.x; i < GG * 64; i += blockDim.x) sp[i] = 0.f;
    __syncthreads();
    const int j = threadIdx.x & 63;
    const float bj = bias[j], sc = ss[j], shf = ss[64 + j];
    const int total = NN * 64;
    const int stride = gridDim.x * blockDim.x;
    for (int idx = blockIdx.x * blockDim.x + threadIdx.x; idx < total; idx += stride) {
        int n = idx >> 6;
        int g = batch[n];
        float v = (agg[idx] + bj) * sc + shf;
        v *= rsqrtf(cnt[g]);
        v = v > 0.f ? v : SLOPE_ACT * v;
        atomicAdd(&sp[g * 64 + j], v);
        xcur[idx] += v;
    }
    __syncthreads();
    for (int i = threadIdx.x; i < GG * 64; i += blockDim.x)
        if (sp[i] != 0.f) atomicAdd(&pool[i], sp[i]);
}

// ---- readout head: concat-pool GEMM + softmax + argmax ----
__global__ void k_head(const float* __restrict__ pools,
                       const float* __restrict__ cnt,
                       const float* __restrict__ Wr,
                       const float* __restrict__ br,
                       float* __restrict__ out) {
    __shared__ float risk[GG * NCLS];
    int t = threadIdx.x;
    if (t < GG * NCLS) {
        int g = t / NCLS, c = t % NCLS;
        float acc = br[c];
        float icnt = 1.f / cnt[g];
        for (int k = 0; k < (LL + 1) * DIM; ++k) {
            int l = k >> 6, j = k & 63;
            float xc = pools[(l * GG + g) * 64 + j] * icnt;
            acc += xc * Wr[k * NCLS + c];
        }
        risk[t] = acc;
        out[t] = acc;
    }
    __syncthreads();
    if (t < GG) {
        float r0 = risk[t * 2], r1 = risk[t * 2 + 1];
        float m = fmaxf(r0, r1);
        float e0 = expf(r0 - m), e1 = expf(r1 - m);
        float s = e0 + e1;
        out[GG * NCLS + t * 2] = e0 / s;
        out[GG * NCLS + t * 2 + 1] = e1 / s;
        out[2 * GG * NCLS + t] = (r1 > r0) ? 1.f : 0.f;   // argmax, first-max on ties
    }
}

extern "C" void kernel_launch(void* const* d_in, const int* in_sizes, int n_in,
                              void* d_out, int out_size, void* d_ws, size_t ws_size,
                              hipStream_t stream) {
    const float* x     = (const float*)d_in[0];
    const int*   ei    = (const int*)d_in[1];
    const int*   batch = (const int*)d_in[2];
    // d_in[3] = n_graphs (compile-time GG)
    const float* W     = (const float*)d_in[4];
    const float* asrc  = (const float*)d_in[5];
    const float* adst  = (const float*)d_in[6];
    const float* bias  = (const float*)d_in[7];
    const float* gamma = (const float*)d_in[8];
    const float* beta  = (const float*)d_in[9];
    const float* Wr    = (const float*)d_in[10];
    const float* br    = (const float*)d_in[11];
    float* out = (float*)d_out;

    char* ws = (char*)d_ws;
    size_t off = 0;
    auto alloc = [&](size_t bytes) {
        void* p = ws + off;
        off += (bytes + 255) & ~(size_t)255;
        return p;
    };
    float* xcur      = (float*)alloc((size_t)NN * 64 * 4);
    float* h         = (float*)alloc((size_t)NN * 64 * 4);
    float* agg       = (float*)alloc((size_t)NN * 64 * 4);
    float* es        = (float*)alloc((size_t)NN * 4 * 4);
    float* ed        = (float*)alloc((size_t)NN * 4 * 4);
    int*   row_start = (int*)alloc((size_t)(NN + 1) * 4);
    int*   ssrc      = (int*)alloc((size_t)EE * 4);
    double* bnsum    = (double*)alloc(128 * 8);
    float* ss        = (float*)alloc(128 * 4);
    float* pools     = (float*)alloc((size_t)(LL + 1) * GG * 64 * 4);
    float* cnt       = (float*)alloc((size_t)GG * 4);
    (void)ws_size; (void)in_sizes; (void)n_in; (void)out_size;

    // CSR-build scratch aliases agg (dead until k_gat_agg, which overwrites it)
    int* deg     = (int*)agg;
    int* cursor  = (int*)agg + NN;
    int* bsum    = (int*)agg + 2 * NN;
    int* bsum_sc = (int*)agg + 2 * NN + 256;

    hipMemcpyAsync(xcur, x, (size_t)NN * 64 * 4, hipMemcpyDeviceToDevice, stream);
    hipMemsetAsync(pools, 0, (size_t)(LL + 1) * GG * 64 * 4, stream);
    hipMemsetAsync(cnt, 0, (size_t)GG * 4, stream);
    hipMemsetAsync(deg, 0, (size_t)NN * 4, stream);

    // ---- build CSR (once; reused by all 3 layers) ----
    k_hist<<<(EE + 255) / 256, 256, 0, stream>>>(ei, deg);
    k_scan1<<<NSCAN, 256, 0, stream>>>(deg, row_start, bsum);
    k_scan2<<<1, 128, 0, stream>>>(bsum, bsum_sc);
    k_scan3<<<(NN + 255) / 256, 256, 0, stream>>>(row_start, bsum_sc);
    hipMemcpyAsync(cursor, row_start, (size_t)NN * 4, hipMemcpyDeviceToDevice, stream);
    k_fill<<<(EE + 255) / 256, 256, 0, stream>>>(ei, cursor, ssrc);

    k_pool0<<<2048, 256, 0, stream>>>(x, batch, pools, cnt);

    for (int l = 0; l < LL; ++l) {
        hipMemsetAsync(bnsum, 0, 128 * 8, stream);
        k_gemm<<<NN / 16, 256, 0, stream>>>(xcur, W + l * DIM * DIM,
                                            asrc + l * HH * CC, adst + l * HH * CC,
                                            h, es, ed);
        k_gat_agg<<<NN / 4, 256, 0, stream>>>(row_start, ssrc, es, ed, h, agg);
        k_bn_reduce<<<1024, 256, 0, stream>>>(agg, bias + l * DIM, bnsum);
        k_bn_final<<<1, 64, 0, stream>>>(bnsum, gamma + l * DIM, beta + l * DIM, ss);
        k_norm_act<<<2048, 256, 0, stream>>>(agg, bias + l * DIM, ss, batch, cnt,
                                             xcur, pools + (size_t)(l + 1) * GG * 64);
    }

    k_head<<<1, 64, 0, stream>>>(pools, cnt, Wr, br, out);
}

// Round 3
// 937.671 us; speedup vs baseline: 3.7577x; 1.2210x over previous
//
#include <hip/hip_runtime.h>

// Problem constants (fixed by the reference)
constexpr int NN   = 100000;   // nodes
constexpr int EE   = 1600000;  // edges
constexpr int DIM  = 64;
constexpr int HH   = 4;        // heads
constexpr int CC   = 16;       // channels / head
constexpr int LL   = 3;        // layers
constexpr int GG   = 16;       // graphs
constexpr int NCLS = 2;
constexpr float SLOPE_ATT = 0.2f;
constexpr float SLOPE_ACT = 0.01f;
constexpr float EPS = 1e-5f;

constexpr int SCAN_CHUNK = 1024;
constexpr int NSCAN = (NN + SCAN_CHUNK - 1) / SCAN_CHUNK;   // 98

__device__ __forceinline__ float lrelu_att(float v) { return v > 0.f ? v : SLOPE_ATT * v; }

// ---- pool of x0 + node counts per graph ----
__global__ __launch_bounds__(256) void k_pool0(const float* __restrict__ x,
                                               const int* __restrict__ batch,
                                               float* __restrict__ pool0,
                                               float* __restrict__ cnt) {
    __shared__ float sp[GG * DIM];
    __shared__ float sc[GG];
    for (int i = threadIdx.x; i < GG * DIM; i += blockDim.x) sp[i] = 0.f;
    if (threadIdx.x < GG) sc[threadIdx.x] = 0.f;
    __syncthreads();
    const int total = NN * DIM;
    const int stride = gridDim.x * blockDim.x;
    for (int idx = blockIdx.x * blockDim.x + threadIdx.x; idx < total; idx += stride) {
        int n = idx >> 6, j = idx & 63;
        int g = batch[n];
        atomicAdd(&sp[g * DIM + j], x[idx]);
        if (j == 0) atomicAdd(&sc[g], 1.f);
    }
    __syncthreads();
    for (int i = threadIdx.x; i < GG * DIM; i += blockDim.x)
        if (sp[i] != 0.f) atomicAdd(&pool0[i], sp[i]);
    if (threadIdx.x < GG && sc[threadIdx.x] != 0.f) atomicAdd(&cnt[threadIdx.x], sc[threadIdx.x]);
}

// ---- CSR build: histogram of dst ----
__global__ __launch_bounds__(256) void k_hist(const int* __restrict__ ei,
                                              int* __restrict__ deg) {
    int e = blockIdx.x * 256 + threadIdx.x;
    if (e < EE) atomicAdd(&deg[ei[EE + e]], 1);
}

// ---- scan step 1: per-chunk exclusive scan + chunk totals ----
__global__ __launch_bounds__(256) void k_scan1(const int* __restrict__ deg,
                                               int* __restrict__ excl,
                                               int* __restrict__ bsum) {
    __shared__ int sh[256];
    const int b = blockIdx.x, t = threadIdx.x;
    const int i0 = b * SCAN_CHUNK + t * 4;
    int v[4];
#pragma unroll
    for (int i = 0; i < 4; ++i) v[i] = (i0 + i < NN) ? deg[i0 + i] : 0;
    int tsum = v[0] + v[1] + v[2] + v[3];
    sh[t] = tsum;
    __syncthreads();
    for (int o = 1; o < 256; o <<= 1) {
        int x = (t >= o) ? sh[t - o] : 0;
        __syncthreads();
        sh[t] += x;
        __syncthreads();
    }
    if (t == 255) bsum[b] = sh[255];
    int run = sh[t] - tsum;
#pragma unroll
    for (int i = 0; i < 4; ++i) {
        if (i0 + i < NN) excl[i0 + i] = run;
        run += v[i];
    }
}

// ---- scan step 2: exclusive scan of chunk totals (1 block) ----
__global__ void k_scan2(const int* __restrict__ bsum, int* __restrict__ bsum_sc) {
    __shared__ int sh[128];
    const int t = threadIdx.x;
    const int own = (t < NSCAN) ? bsum[t] : 0;
    sh[t] = own;
    __syncthreads();
    for (int o = 1; o < 128; o <<= 1) {
        int x = (t >= o) ? sh[t - o] : 0;
        __syncthreads();
        sh[t] += x;
        __syncthreads();
    }
    if (t < NSCAN) bsum_sc[t] = sh[t] - own;
}

// ---- scan step 3: add chunk offsets, write cursor copy, set sentinel ----
__global__ __launch_bounds__(256) void k_scan3(int* __restrict__ row_start,
                                               const int* __restrict__ bsum_sc,
                                               int* __restrict__ cursor) {
    int i = blockIdx.x * 256 + threadIdx.x;
    if (i < NN) {
        int v = row_start[i] + bsum_sc[i / SCAN_CHUNK];
        row_start[i] = v;
        cursor[i] = v;
    }
    if (i == 0) row_start[NN] = EE;
}

// ---- CSR fill: place src of each edge into its dst segment ----
__global__ __launch_bounds__(256) void k_fill(const int* __restrict__ ei,
                                              int* __restrict__ cursor,
                                              int* __restrict__ ssrc) {
    int e = blockIdx.x * 256 + threadIdx.x;
    if (e >= EE) return;
    int d = ei[EE + e], s = ei[e];
    int pos = atomicAdd(&cursor[d], 1);
    ssrc[pos] = s;
}

// ---- h = x @ W with 4x4 register tiling (64 rows/block) + fused att logits ----
__global__ __launch_bounds__(256) void k_gemm(const float* __restrict__ xin,
                                              const float* __restrict__ Wl,
                                              const float* __restrict__ asrc,
                                              const float* __restrict__ adst,
                                              float* __restrict__ h,
                                              float* __restrict__ es,
                                              float* __restrict__ ed) {
    __shared__ float Ws[DIM][DIM];       // 16 KB, row-major (k, j)
    __shared__ float xsT[DIM][DIM + 1];  // transposed x tile: [k][row], padded
    const int tid = threadIdx.x;
    const int row0 = blockIdx.x * 64;

    const float4* W4 = (const float4*)Wl;
#pragma unroll
    for (int i = 0; i < 4; ++i) ((float4*)Ws)[tid + 256 * i] = W4[tid + 256 * i];

#pragma unroll
    for (int i = 0; i < 4; ++i) {
        int idx4 = tid + 256 * i;         // float4 index in 64x64 tile
        int r = idx4 >> 4, c4 = idx4 & 15;
        int grow = row0 + r;
        float4 v = make_float4(0.f, 0.f, 0.f, 0.f);
        if (grow < NN) v = ((const float4*)xin)[grow * 16 + c4];
        xsT[c4 * 4 + 0][r] = v.x;
        xsT[c4 * 4 + 1][r] = v.y;
        xsT[c4 * 4 + 2][r] = v.z;
        xsT[c4 * 4 + 3][r] = v.w;
    }
    __syncthreads();

    const int tc = tid & 15, tr = tid >> 4;   // cols 4tc.., rows 4tr..
    float acc[4][4] = {};
#pragma unroll
    for (int k = 0; k < DIM; ++k) {
        float4 wv = *(const float4*)(&Ws[k][tc * 4]);
        float4 xv = *(const float4*)(&xsT[k][tr * 4]);   // rows 4tr..4tr+3 (pad keeps 16B align per row? pitch 65 floats)
        acc[0][0] = fmaf(xv.x, wv.x, acc[0][0]);
        acc[0][1] = fmaf(xv.x, wv.y, acc[0][1]);
        acc[0][2] = fmaf(xv.x, wv.z, acc[0][2]);
        acc[0][3] = fmaf(xv.x, wv.w, acc[0][3]);
        acc[1][0] = fmaf(xv.y, wv.x, acc[1][0]);
        acc[1][1] = fmaf(xv.y, wv.y, acc[1][1]);
        acc[1][2] = fmaf(xv.y, wv.z, acc[1][2]);
        acc[1][3] = fmaf(xv.y, wv.w, acc[1][3]);
        acc[2][0] = fmaf(xv.z, wv.x, acc[2][0]);
        acc[2][1] = fmaf(xv.z, wv.y, acc[2][1]);
        acc[2][2] = fmaf(xv.z, wv.z, acc[2][2]);
        acc[2][3] = fmaf(xv.z, wv.w, acc[2][3]);
        acc[3][0] = fmaf(xv.w, wv.x, acc[3][0]);
        acc[3][1] = fmaf(xv.w, wv.y, acc[3][1]);
        acc[3][2] = fmaf(xv.w, wv.z, acc[3][2]);
        acc[3][3] = fmaf(xv.w, wv.w, acc[3][3]);
    }

    float a_s[4], a_d[4];
#pragma unroll
    for (int c = 0; c < 4; ++c) { a_s[c] = asrc[4 * tc + c]; a_d[c] = adst[4 * tc + c]; }

#pragma unroll
    for (int r = 0; r < 4; ++r) {
        int n = row0 + 4 * tr + r;
        if (n < NN) {
            *(float4*)(h + n * 64 + 4 * tc) =
                make_float4(acc[r][0], acc[r][1], acc[r][2], acc[r][3]);
            float ps = acc[r][0] * a_s[0] + acc[r][1] * a_s[1] +
                       acc[r][2] * a_s[2] + acc[r][3] * a_s[3];
            float pd = acc[r][0] * a_d[0] + acc[r][1] * a_d[1] +
                       acc[r][2] * a_d[2] + acc[r][3] * a_d[3];
            ps += __shfl_xor(ps, 1); ps += __shfl_xor(ps, 2);
            pd += __shfl_xor(pd, 1); pd += __shfl_xor(pd, 2);
            if ((tc & 3) == 0) {
                es[n * 4 + (tc >> 2)] = ps;
                ed[n * 4 + (tc >> 2)] = pd;
            }
        }
    }
}

// ---- fused GAT aggregation: one wave per dst node ----
// fast path (deg<=64): single gather of es, alphas cached in LDS,
// inner loop = 4 edges/iter, 16 lanes x float4 per edge.
__global__ __launch_bounds__(256) void k_gat_agg(const int* __restrict__ row_start,
                                                 const int* __restrict__ ssrc,
                                                 const float* __restrict__ es,
                                                 const float* __restrict__ ed,
                                                 const float* __restrict__ h,
                                                 float* __restrict__ agg) {
    __shared__ int   sbuf[4][64];
    __shared__ float exbuf[4][64][4];   // [wave][slot][head]
    const int wid = threadIdx.x >> 6;
    const int j   = threadIdx.x & 63;
    const int n   = blockIdx.x * 4 + wid;          // grid = NN/4 exact
    const int base = row_start[n];
    const int deg  = row_start[n + 1] - base;
    const float4 edv = *(const float4*)(ed + n * 4);

    if (deg <= 64) {
        int s = 0;
        float4 al = make_float4(-INFINITY, -INFINITY, -INFINITY, -INFINITY);
        if (j < deg) {
            s = ssrc[base + j];
            float4 ev = *(const float4*)(es + s * 4);
            al.x = lrelu_att(ev.x + edv.x);
            al.y = lrelu_att(ev.y + edv.y);
            al.z = lrelu_att(ev.z + edv.z);
            al.w = lrelu_att(ev.w + edv.w);
        }
        sbuf[wid][j] = s;
        float4 mx = al;
#pragma unroll
        for (int o = 1; o < 64; o <<= 1) {
            mx.x = fmaxf(mx.x, __shfl_xor(mx.x, o));
            mx.y = fmaxf(mx.y, __shfl_xor(mx.y, o));
            mx.z = fmaxf(mx.z, __shfl_xor(mx.z, o));
            mx.w = fmaxf(mx.w, __shfl_xor(mx.w, o));
        }
        float4 ex = make_float4(0.f, 0.f, 0.f, 0.f);
        if (j < deg) {
            ex.x = __expf(al.x - mx.x);
            ex.y = __expf(al.y - mx.y);
            ex.z = __expf(al.z - mx.z);
            ex.w = __expf(al.w - mx.w);
        }
        *(float4*)&exbuf[wid][j][0] = ex;
        float4 den = ex;
#pragma unroll
        for (int o = 1; o < 64; o <<= 1) {
            den.x += __shfl_xor(den.x, o);
            den.y += __shfl_xor(den.y, o);
            den.z += __shfl_xor(den.z, o);
            den.w += __shfl_xor(den.w, o);
        }
        const int jj = j & 15, grp = j >> 4, hq = jj >> 2;
        float4 acc = make_float4(0.f, 0.f, 0.f, 0.f);
        const int iters = (deg + 3) & ~3;
        for (int i = grp; i < iters; i += 4) {
            int si = sbuf[wid][i];
            float exv = exbuf[wid][i][hq];
            float4 hv = *(const float4*)(h + si * 64 + jj * 4);
            acc.x = fmaf(exv, hv.x, acc.x);
            acc.y = fmaf(exv, hv.y, acc.y);
            acc.z = fmaf(exv, hv.z, acc.z);
            acc.w = fmaf(exv, hv.w, acc.w);
        }
#pragma unroll
        for (int o = 16; o < 64; o <<= 1) {
            acc.x += __shfl_xor(acc.x, o);
            acc.y += __shfl_xor(acc.y, o);
            acc.z += __shfl_xor(acc.z, o);
            acc.w += __shfl_xor(acc.w, o);
        }
        if (grp == 0) {
            float d = hq == 0 ? den.x : hq == 1 ? den.y : hq == 2 ? den.z : den.w;
            float inv = 1.f / (d + 1e-16f);
            *(float4*)(agg + n * 64 + jj * 4) =
                make_float4(acc.x * inv, acc.y * inv, acc.z * inv, acc.w * inv);
        }
    } else {
        // slow path: generic two-pass (rare)
        const int hh = j >> 4;
        float4 mx = make_float4(-INFINITY, -INFINITY, -INFINITY, -INFINITY);
        for (int c0 = 0; c0 < deg; c0 += 64) {
            if (j < deg - c0) {
                int s = ssrc[base + c0 + j];
                float4 ev = *(const float4*)(es + s * 4);
                mx.x = fmaxf(mx.x, lrelu_att(ev.x + edv.x));
                mx.y = fmaxf(mx.y, lrelu_att(ev.y + edv.y));
                mx.z = fmaxf(mx.z, lrelu_att(ev.z + edv.z));
                mx.w = fmaxf(mx.w, lrelu_att(ev.w + edv.w));
            }
        }
#pragma unroll
        for (int o = 1; o < 64; o <<= 1) {
            mx.x = fmaxf(mx.x, __shfl_xor(mx.x, o));
            mx.y = fmaxf(mx.y, __shfl_xor(mx.y, o));
            mx.z = fmaxf(mx.z, __shfl_xor(mx.z, o));
            mx.w = fmaxf(mx.w, __shfl_xor(mx.w, o));
        }
        float acc = 0.f;
        float4 den = make_float4(0.f, 0.f, 0.f, 0.f);
        for (int c0 = 0; c0 < deg; c0 += 64) {
            int cn = min(64, deg - c0);
            float4 ex = make_float4(0.f, 0.f, 0.f, 0.f);
            int s = 0;
            if (j < cn) {
                s = ssrc[base + c0 + j];
                float4 ev = *(const float4*)(es + s * 4);
                ex.x = __expf(lrelu_att(ev.x + edv.x) - mx.x);
                ex.y = __expf(lrelu_att(ev.y + edv.y) - mx.y);
                ex.z = __expf(lrelu_att(ev.z + edv.z) - mx.z);
                ex.w = __expf(lrelu_att(ev.w + edv.w) - mx.w);
            }
            den.x += ex.x; den.y += ex.y; den.z += ex.z; den.w += ex.w;
            sbuf[wid][j] = s;
            *(float4*)&exbuf[wid][j][0] = ex;
            for (int i = 0; i < cn; ++i) {
                int si = sbuf[wid][i];
                acc = fmaf(exbuf[wid][i][hh], h[si * 64 + j], acc);
            }
        }
#pragma unroll
        for (int o = 1; o < 64; o <<= 1) {
            den.x += __shfl_xor(den.x, o);
            den.y += __shfl_xor(den.y, o);
            den.z += __shfl_xor(den.z, o);
            den.w += __shfl_xor(den.w, o);
        }
        float d = hh == 0 ? den.x : hh == 1 ? den.y : hh == 2 ? den.z : den.w;
        agg[n * 64 + j] = acc / (d + 1e-16f);
    }
}

// ---- BatchNorm statistics (sum, sumsq per channel), f64 accumulators ----
__global__ __launch_bounds__(256) void k_bn_reduce(const float* __restrict__ agg,
                                                   const float* __restrict__ bias,
                                                   double* __restrict__ bnsum) {
    const int j = threadIdx.x & 63, r = threadIdx.x >> 6;
    const float bj = bias[j];
    double ds = 0.0, ds2 = 0.0;
    const int total = NN * 64;
    const int stride = gridDim.x * blockDim.x;
    for (int idx = blockIdx.x * blockDim.x + threadIdx.x; idx < total; idx += stride) {
        float v = agg[idx] + bj;
        ds += v;
        ds2 += (double)v * v;
    }
    __shared__ double sh[2][4][64];
    sh[0][r][j] = ds;
    sh[1][r][j] = ds2;
    __syncthreads();
    if (r == 0) {
        double t1 = sh[0][0][j] + sh[0][1][j] + sh[0][2][j] + sh[0][3][j];
        double t2 = sh[1][0][j] + sh[1][1][j] + sh[1][2][j] + sh[1][3][j];
        atomicAdd(&bnsum[j], t1);
        atomicAdd(&bnsum[64 + j], t2);
    }
}

__global__ void k_bn_final(const double* __restrict__ bnsum,
                           const float* __restrict__ gamma,
                           const float* __restrict__ beta,
                           const float* __restrict__ bias,
                           float* __restrict__ ss) {
    int j = threadIdx.x;
    if (j < 64) {
        double mean = bnsum[j] / (double)NN;
        double var = bnsum[64 + j] / (double)NN - mean * mean;
        float sc = (float)(1.0 / sqrt(var + (double)EPS)) * gamma[j];
        ss[j] = sc;
        // fold bias into shift: (v + bias - mean)*sc + beta
        ss[64 + j] = beta[j] + (bias[j] - (float)mean) * sc;
    }
}

// ---- norm + GraphSizeNorm + LeakyReLU + pool + residual (contiguous blocks) ----
constexpr int NA_BLOCKS = 512;
constexpr int NA_NODES = (NN + NA_BLOCKS - 1) / NA_BLOCKS;   // 196
__global__ __launch_bounds__(256) void k_norm_act(const float* __restrict__ agg,
                                                  const float* __restrict__ ss,
                                                  const int* __restrict__ batch,
                                                  const float* __restrict__ cnt,
                                                  float* __restrict__ xcur,
                                                  float* __restrict__ pool) {
    __shared__ float sp[GG * 64];
    for (int i = threadIdx.x; i < GG * 64; i += 256) sp[i] = 0.f;
    __syncthreads();
    const int j = threadIdx.x & 63, r = threadIdx.x >> 6;
    const float sc = ss[j], shf = ss[64 + j];
    const int n0 = blockIdx.x * NA_NODES;
    const int n1 = min(n0 + NA_NODES, NN);
    float racc = 0.f;
    int curg = -1;
    float rinv = 0.f;
    for (int n = n0 + r; n < n1; n += 4) {
        int g = batch[n];
        if (g != curg) {
            if (curg >= 0) atomicAdd(&sp[curg * 64 + j], racc);
            curg = g; racc = 0.f;
            rinv = rsqrtf(cnt[g]);
        }
        float v = (agg[n * 64 + j] * sc + shf) * rinv;
        v = v > 0.f ? v : SLOPE_ACT * v;
        racc += v;
        xcur[n * 64 + j] += v;
    }
    if (curg >= 0) atomicAdd(&sp[curg * 64 + j], racc);
    __syncthreads();
    for (int i = threadIdx.x; i < GG * 64; i += 256)
        if (sp[i] != 0.f) atomicAdd(&pool[i], sp[i]);
}

// ---- readout head ----
__global__ void k_head(const float* __restrict__ pools,
                       const float* __restrict__ cnt,
                       const float* __restrict__ Wr,
                       const float* __restrict__ br,
                       float* __restrict__ out) {
    __shared__ float risk[GG * NCLS];
    int t = threadIdx.x;
    if (t < GG * NCLS) {
        int g = t / NCLS, c = t % NCLS;
        float acc = br[c];
        float icnt = 1.f / cnt[g];
        for (int k = 0; k < (LL + 1) * DIM; ++k) {
            int l = k >> 6, j = k & 63;
            float xc = pools[(l * GG + g) * 64 + j] * icnt;
            acc += xc * Wr[k * NCLS + c];
        }
        risk[t] = acc;
        out[t] = acc;
    }
    __syncthreads();
    if (t < GG) {
        float r0 = risk[t * 2], r1 = risk[t * 2 + 1];
        float m = fmaxf(r0, r1);
        float e0 = expf(r0 - m), e1 = expf(r1 - m);
        float s = e0 + e1;
        out[GG * NCLS + t * 2] = e0 / s;
        out[GG * NCLS + t * 2 + 1] = e1 / s;
        out[2 * GG * NCLS + t] = (r1 > r0) ? 1.f : 0.f;
    }
}

extern "C" void kernel_launch(void* const* d_in, const int* in_sizes, int n_in,
                              void* d_out, int out_size, void* d_ws, size_t ws_size,
                              hipStream_t stream) {
    const float* x     = (const float*)d_in[0];
    const int*   ei    = (const int*)d_in[1];
    const int*   batch = (const int*)d_in[2];
    const float* W     = (const float*)d_in[4];
    const float* asrc  = (const float*)d_in[5];
    const float* adst  = (const float*)d_in[6];
    const float* bias  = (const float*)d_in[7];
    const float* gamma = (const float*)d_in[8];
    const float* beta  = (const float*)d_in[9];
    const float* Wr    = (const float*)d_in[10];
    const float* br    = (const float*)d_in[11];
    float* out = (float*)d_out;

    char* ws = (char*)d_ws;
    size_t off = 0;
    auto alloc = [&](size_t bytes) {
        void* p = ws + off;
        off += (bytes + 255) & ~(size_t)255;
        return p;
    };
    float* xcur      = (float*)alloc((size_t)NN * 64 * 4);
    float* h         = (float*)alloc((size_t)NN * 64 * 4);
    float* agg       = (float*)alloc((size_t)NN * 64 * 4);
    float* es        = (float*)alloc((size_t)NN * 4 * 4);
    float* ed        = (float*)alloc((size_t)NN * 4 * 4);
    int*   row_start = (int*)alloc((size_t)(NN + 1) * 4);
    int*   ssrc      = (int*)alloc((size_t)EE * 4);
    double* bnsum    = (double*)alloc(128 * 8);
    float* ss        = (float*)alloc(128 * 4);
    float* pools     = (float*)alloc((size_t)(LL + 1) * GG * 64 * 4);
    float* cnt       = (float*)alloc((size_t)GG * 4);
    (void)ws_size; (void)in_sizes; (void)n_in; (void)out_size;

    // CSR-build scratch aliases agg (dead until k_gat_agg overwrites it)
    int* deg     = (int*)agg;
    int* cursor  = (int*)agg + NN;
    int* bsum    = (int*)agg + 2 * NN;
    int* bsum_sc = (int*)agg + 2 * NN + 256;

    hipMemcpyAsync(xcur, x, (size_t)NN * 64 * 4, hipMemcpyDeviceToDevice, stream);
    hipMemsetAsync(pools, 0, (size_t)(LL + 1) * GG * 64 * 4, stream);
    hipMemsetAsync(cnt, 0, (size_t)GG * 4, stream);
    hipMemsetAsync(deg, 0, (size_t)NN * 4, stream);

    // ---- build CSR (once; reused by all 3 layers) ----
    k_hist<<<(EE + 255) / 256, 256, 0, stream>>>(ei, deg);
    k_scan1<<<NSCAN, 256, 0, stream>>>(deg, row_start, bsum);
    k_scan2<<<1, 128, 0, stream>>>(bsum, bsum_sc);
    k_scan3<<<(NN + 255) / 256, 256, 0, stream>>>(row_start, bsum_sc, cursor);
    k_fill<<<(EE + 255) / 256, 256, 0, stream>>>(ei, cursor, ssrc);

    k_pool0<<<2048, 256, 0, stream>>>(x, batch, pools, cnt);

    for (int l = 0; l < LL; ++l) {
        hipMemsetAsync(bnsum, 0, 128 * 8, stream);
        k_gemm<<<(NN + 63) / 64, 256, 0, stream>>>(xcur, W + l * DIM * DIM,
                                                   asrc + l * HH * CC, adst + l * HH * CC,
                                                   h, es, ed);
        k_gat_agg<<<NN / 4, 256, 0, stream>>>(row_start, ssrc, es, ed, h, agg);
        k_bn_reduce<<<1024, 256, 0, stream>>>(agg, bias + l * DIM, bnsum);
        k_bn_final<<<1, 64, 0, stream>>>(bnsum, gamma + l * DIM, beta + l * DIM,
                                         bias + l * DIM, ss);
        k_norm_act<<<NA_BLOCKS, 256, 0, stream>>>(agg, ss, batch, cnt,
                                                  xcur, pools + (size_t)(l + 1) * GG * 64);
    }

    k_head<<<1, 64, 0, stream>>>(pools, cnt, Wr, br, out);
}

// Round 4
// 758.323 us; speedup vs baseline: 4.6465x; 1.2365x over previous
//
#include <hip/hip_runtime.h>

// Problem constants (fixed by the reference)
constexpr int NN   = 100000;   // nodes
constexpr int EE   = 1600000;  // edges
constexpr int DIM  = 64;
constexpr int HH   = 4;        // heads
constexpr int CC   = 16;       // channels / head
constexpr int LL   = 3;        // layers
constexpr int GG   = 16;       // graphs
constexpr int NCLS = 2;
constexpr float SLOPE_ATT = 0.2f;
constexpr float SLOPE_ACT = 0.01f;
constexpr float EPS = 1e-5f;

constexpr int SCAN_CHUNK = 1024;
constexpr int NSCAN = (NN + SCAN_CHUNK - 1) / SCAN_CHUNK;   // 98

__device__ __forceinline__ float lrelu_att(float v) { return v > 0.f ? v : SLOPE_ATT * v; }

// ---- pool of x0 + node counts per graph + xcur init (fused memcpy) ----
__global__ __launch_bounds__(256) void k_pool0(const float* __restrict__ x,
                                               const int* __restrict__ batch,
                                               float* __restrict__ pool0,
                                               float* __restrict__ cnt,
                                               float* __restrict__ xcur) {
    __shared__ float sp[GG * DIM];
    __shared__ float sc[GG];
    for (int i = threadIdx.x; i < GG * DIM; i += blockDim.x) sp[i] = 0.f;
    if (threadIdx.x < GG) sc[threadIdx.x] = 0.f;
    __syncthreads();
    const int total = NN * DIM;
    const int stride = gridDim.x * blockDim.x;
    for (int idx = blockIdx.x * blockDim.x + threadIdx.x; idx < total; idx += stride) {
        int n = idx >> 6, j = idx & 63;
        int g = batch[n];
        float v = x[idx];
        xcur[idx] = v;
        atomicAdd(&sp[g * DIM + j], v);
        if (j == 0) atomicAdd(&sc[g], 1.f);
    }
    __syncthreads();
    for (int i = threadIdx.x; i < GG * DIM; i += blockDim.x)
        if (sp[i] != 0.f) atomicAdd(&pool0[i], sp[i]);
    if (threadIdx.x < GG && sc[threadIdx.x] != 0.f) atomicAdd(&cnt[threadIdx.x], sc[threadIdx.x]);
}

// ---- CSR build: histogram of dst (int4 vectorized) ----
__global__ __launch_bounds__(256) void k_hist(const int* __restrict__ ei,
                                              int* __restrict__ deg) {
    int i = blockIdx.x * 256 + threadIdx.x;
    if (i < EE / 4) {
        int4 d = ((const int4*)(ei + EE))[i];
        atomicAdd(&deg[d.x], 1);
        atomicAdd(&deg[d.y], 1);
        atomicAdd(&deg[d.z], 1);
        atomicAdd(&deg[d.w], 1);
    }
}

// ---- scan step 1: per-chunk exclusive scan + chunk totals ----
__global__ __launch_bounds__(256) void k_scan1(const int* __restrict__ deg,
                                               int* __restrict__ excl,
                                               int* __restrict__ bsum) {
    __shared__ int sh[256];
    const int b = blockIdx.x, t = threadIdx.x;
    const int i0 = b * SCAN_CHUNK + t * 4;
    int v[4];
#pragma unroll
    for (int i = 0; i < 4; ++i) v[i] = (i0 + i < NN) ? deg[i0 + i] : 0;
    int tsum = v[0] + v[1] + v[2] + v[3];
    sh[t] = tsum;
    __syncthreads();
    for (int o = 1; o < 256; o <<= 1) {
        int x = (t >= o) ? sh[t - o] : 0;
        __syncthreads();
        sh[t] += x;
        __syncthreads();
    }
    if (t == 255) bsum[b] = sh[255];
    int run = sh[t] - tsum;
#pragma unroll
    for (int i = 0; i < 4; ++i) {
        if (i0 + i < NN) excl[i0 + i] = run;
        run += v[i];
    }
}

// ---- scan step 2: exclusive scan of chunk totals (1 block) ----
__global__ void k_scan2(const int* __restrict__ bsum, int* __restrict__ bsum_sc) {
    __shared__ int sh[128];
    const int t = threadIdx.x;
    const int own = (t < NSCAN) ? bsum[t] : 0;
    sh[t] = own;
    __syncthreads();
    for (int o = 1; o < 128; o <<= 1) {
        int x = (t >= o) ? sh[t - o] : 0;
        __syncthreads();
        sh[t] += x;
        __syncthreads();
    }
    if (t < NSCAN) bsum_sc[t] = sh[t] - own;
}

// ---- scan step 3: add chunk offsets, write cursor copy, set sentinel ----
__global__ __launch_bounds__(256) void k_scan3(int* __restrict__ row_start,
                                               const int* __restrict__ bsum_sc,
                                               int* __restrict__ cursor) {
    int i = blockIdx.x * 256 + threadIdx.x;
    if (i < NN) {
        int v = row_start[i] + bsum_sc[i / SCAN_CHUNK];
        row_start[i] = v;
        cursor[i] = v;
    }
    if (i == 0) row_start[NN] = EE;
}

// ---- CSR fill, XCD-range partitioned: group g claims dst in its 1/8 range ----
// Each of 8 groups scans all edges; writes land in a contiguous ~800KB ssrc
// region that stays in one L2 -> full-line write combining.
constexpr int FILL_NBLK = 256;                       // blocks per group
constexpr int DRANGE = (NN + 7) / 8;                 // 12500 dst per group
__global__ __launch_bounds__(256) void k_fill(const int* __restrict__ ei,
                                              int* __restrict__ cursor,
                                              int* __restrict__ ssrc) {
    const int g = blockIdx.x & 7;
    const int blk = blockIdx.x >> 3;
    const int dlo = g * DRANGE, dhi = min(dlo + DRANGE, NN);
    const int stride = FILL_NBLK * 256;
    for (int e = blk * 256 + threadIdx.x; e < EE; e += stride) {
        int d = ei[EE + e];
        if (d >= dlo && d < dhi) {
            int s = ei[e];
            int pos = atomicAdd(&cursor[d], 1);
            ssrc[pos] = s;
        }
    }
}

// ---- h = x @ W, 4x4 register tiling, XOR-swizzled x^T tile (b128 both sides) ----
__global__ __launch_bounds__(256) void k_gemm(const float* __restrict__ xin,
                                              const float* __restrict__ Wl,
                                              const float* __restrict__ asrc,
                                              const float* __restrict__ adst,
                                              float* __restrict__ h,
                                              float* __restrict__ es,
                                              float* __restrict__ ed) {
    __shared__ float Ws[DIM][DIM];   // 16 KB, row-major (k, j)
    __shared__ float xsT[DIM][DIM];  // transposed x tile, col-swizzled
    const int tid = threadIdx.x;
    const int row0 = blockIdx.x * 64;

    const float4* W4 = (const float4*)Wl;
#pragma unroll
    for (int i = 0; i < 4; ++i) ((float4*)Ws)[tid + 256 * i] = W4[tid + 256 * i];

#pragma unroll
    for (int i = 0; i < 4; ++i) {
        int idx4 = tid + 256 * i;         // float4 index in 64x64 tile
        int r = idx4 >> 4, c4 = idx4 & 15;   // row r, k-chunk c4 (k = 4*c4+q)
        int grow = row0 + r;
        float4 v = make_float4(0.f, 0.f, 0.f, 0.f);
        if (grow < NN) v = ((const float4*)xin)[grow * 16 + c4];
        // col = ((r>>2) ^ ((k>>2)&15))*4 + (r&3);  k>>2 == c4 for q in 0..3
        int col = (((r >> 2) ^ c4) << 2) | (r & 3);
        xsT[c4 * 4 + 0][col] = v.x;
        xsT[c4 * 4 + 1][col] = v.y;
        xsT[c4 * 4 + 2][col] = v.z;
        xsT[c4 * 4 + 3][col] = v.w;
    }
    __syncthreads();

    const int tc = tid & 15, tr = tid >> 4;   // cols 4tc.., rows 4tr..
    float acc[4][4] = {};
#pragma unroll 8
    for (int k = 0; k < DIM; ++k) {
        int kc = (k >> 2) & 15;
        float4 wv = *(const float4*)(&Ws[k][tc * 4]);
        float4 xv = *(const float4*)(&xsT[k][(tr ^ kc) * 4]);   // rows 4tr..4tr+3
        acc[0][0] = fmaf(xv.x, wv.x, acc[0][0]);
        acc[0][1] = fmaf(xv.x, wv.y, acc[0][1]);
        acc[0][2] = fmaf(xv.x, wv.z, acc[0][2]);
        acc[0][3] = fmaf(xv.x, wv.w, acc[0][3]);
        acc[1][0] = fmaf(xv.y, wv.x, acc[1][0]);
        acc[1][1] = fmaf(xv.y, wv.y, acc[1][1]);
        acc[1][2] = fmaf(xv.y, wv.z, acc[1][2]);
        acc[1][3] = fmaf(xv.y, wv.w, acc[1][3]);
        acc[2][0] = fmaf(xv.z, wv.x, acc[2][0]);
        acc[2][1] = fmaf(xv.z, wv.y, acc[2][1]);
        acc[2][2] = fmaf(xv.z, wv.z, acc[2][2]);
        acc[2][3] = fmaf(xv.z, wv.w, acc[2][3]);
        acc[3][0] = fmaf(xv.w, wv.x, acc[3][0]);
        acc[3][1] = fmaf(xv.w, wv.y, acc[3][1]);
        acc[3][2] = fmaf(xv.w, wv.z, acc[3][2]);
        acc[3][3] = fmaf(xv.w, wv.w, acc[3][3]);
    }

    float a_s[4], a_d[4];
#pragma unroll
    for (int c = 0; c < 4; ++c) { a_s[c] = asrc[4 * tc + c]; a_d[c] = adst[4 * tc + c]; }

#pragma unroll
    for (int r = 0; r < 4; ++r) {
        int n = row0 + 4 * tr + r;
        if (n < NN) {
            *(float4*)(h + n * 64 + 4 * tc) =
                make_float4(acc[r][0], acc[r][1], acc[r][2], acc[r][3]);
            float ps = acc[r][0] * a_s[0] + acc[r][1] * a_s[1] +
                       acc[r][2] * a_s[2] + acc[r][3] * a_s[3];
            float pd = acc[r][0] * a_d[0] + acc[r][1] * a_d[1] +
                       acc[r][2] * a_d[2] + acc[r][3] * a_d[3];
            ps += __shfl_xor(ps, 1); ps += __shfl_xor(ps, 2);
            pd += __shfl_xor(pd, 1); pd += __shfl_xor(pd, 2);
            if ((tc & 3) == 0) {
                es[n * 4 + (tc >> 2)] = ps;
                ed[n * 4 + (tc >> 2)] = pd;
            }
        }
    }
}

// ---- fused GAT aggregation: 16-lane group per dst node, 16 nodes/block ----
// lane owns channels [4*lane16, 4*lane16+3]; 2 edge slots/lane covers deg<=32.
__global__ __launch_bounds__(256) void k_gat_agg(const int* __restrict__ row_start,
                                                 const int* __restrict__ ssrc,
                                                 const float* __restrict__ es,
                                                 const float* __restrict__ ed,
                                                 const float* __restrict__ h,
                                                 float* __restrict__ agg) {
    __shared__ int   sbuf[16][33];       // [group][slot], padded
    __shared__ float exbuf[16][33][4];   // [group][slot][head], padded
    const int lane16 = threadIdx.x & 15;
    const int grp    = threadIdx.x >> 4;
    const int n = blockIdx.x * 16 + grp;            // NN % 16 == 0
    const int base = row_start[n];
    const int deg  = row_start[n + 1] - base;
    const float4 edv = *(const float4*)(ed + n * 4);
    const int hq = lane16 >> 2;

    float4 accv = make_float4(0.f, 0.f, 0.f, 0.f);
    float4 den  = make_float4(0.f, 0.f, 0.f, 0.f);

    if (deg <= 32) {
        // ---- fast path: single chunk, es gathered once ----
        int s0 = 0, s1 = 0;
        float4 al0 = make_float4(-INFINITY, -INFINITY, -INFINITY, -INFINITY);
        float4 al1 = al0;
        if (lane16 < deg) {
            s0 = ssrc[base + lane16];
            float4 ev = *(const float4*)(es + s0 * 4);
            al0.x = lrelu_att(ev.x + edv.x); al0.y = lrelu_att(ev.y + edv.y);
            al0.z = lrelu_att(ev.z + edv.z); al0.w = lrelu_att(ev.w + edv.w);
        }
        if (lane16 + 16 < deg) {
            s1 = ssrc[base + 16 + lane16];
            float4 ev = *(const float4*)(es + s1 * 4);
            al1.x = lrelu_att(ev.x + edv.x); al1.y = lrelu_att(ev.y + edv.y);
            al1.z = lrelu_att(ev.z + edv.z); al1.w = lrelu_att(ev.w + edv.w);
        }
        float4 mx = make_float4(fmaxf(al0.x, al1.x), fmaxf(al0.y, al1.y),
                                fmaxf(al0.z, al1.z), fmaxf(al0.w, al1.w));
#pragma unroll
        for (int o = 1; o < 16; o <<= 1) {
            mx.x = fmaxf(mx.x, __shfl_xor(mx.x, o, 16));
            mx.y = fmaxf(mx.y, __shfl_xor(mx.y, o, 16));
            mx.z = fmaxf(mx.z, __shfl_xor(mx.z, o, 16));
            mx.w = fmaxf(mx.w, __shfl_xor(mx.w, o, 16));
        }
        float4 ex0 = make_float4(0.f, 0.f, 0.f, 0.f), ex1 = ex0;
        if (lane16 < deg) {
            ex0.x = __expf(al0.x - mx.x); ex0.y = __expf(al0.y - mx.y);
            ex0.z = __expf(al0.z - mx.z); ex0.w = __expf(al0.w - mx.w);
        }
        if (lane16 + 16 < deg) {
            ex1.x = __expf(al1.x - mx.x); ex1.y = __expf(al1.y - mx.y);
            ex1.z = __expf(al1.z - mx.z); ex1.w = __expf(al1.w - mx.w);
        }
        den.x = ex0.x + ex1.x; den.y = ex0.y + ex1.y;
        den.z = ex0.z + ex1.z; den.w = ex0.w + ex1.w;
        sbuf[grp][lane16] = s0;
        sbuf[grp][lane16 + 16] = s1;
        *(float4*)&exbuf[grp][lane16][0] = ex0;
        *(float4*)&exbuf[grp][lane16 + 16][0] = ex1;
        // wave-coherent LDS within 16-lane group: no barrier needed
#pragma unroll 4
        for (int i = 0; i < deg; ++i) {
            int si = sbuf[grp][i];
            float e = exbuf[grp][i][hq];
            float4 hv = *(const float4*)(h + si * 64 + lane16 * 4);
            accv.x = fmaf(e, hv.x, accv.x);
            accv.y = fmaf(e, hv.y, accv.y);
            accv.z = fmaf(e, hv.z, accv.z);
            accv.w = fmaf(e, hv.w, accv.w);
        }
    } else {
        // ---- slow path: chunked two-pass (rare: deg > 32) ----
        float4 mx = make_float4(-INFINITY, -INFINITY, -INFINITY, -INFINITY);
        for (int c0 = 0; c0 < deg; c0 += 16) {
            if (c0 + lane16 < deg) {
                int s = ssrc[base + c0 + lane16];
                float4 ev = *(const float4*)(es + s * 4);
                mx.x = fmaxf(mx.x, lrelu_att(ev.x + edv.x));
                mx.y = fmaxf(mx.y, lrelu_att(ev.y + edv.y));
                mx.z = fmaxf(mx.z, lrelu_att(ev.z + edv.z));
                mx.w = fmaxf(mx.w, lrelu_att(ev.w + edv.w));
            }
        }
#pragma unroll
        for (int o = 1; o < 16; o <<= 1) {
            mx.x = fmaxf(mx.x, __shfl_xor(mx.x, o, 16));
            mx.y = fmaxf(mx.y, __shfl_xor(mx.y, o, 16));
            mx.z = fmaxf(mx.z, __shfl_xor(mx.z, o, 16));
            mx.w = fmaxf(mx.w, __shfl_xor(mx.w, o, 16));
        }
        for (int c0 = 0; c0 < deg; c0 += 16) {
            int cn = min(16, deg - c0);
            float4 ex = make_float4(0.f, 0.f, 0.f, 0.f);
            int s = 0;
            if (lane16 < cn) {
                s = ssrc[base + c0 + lane16];
                float4 ev = *(const float4*)(es + s * 4);
                ex.x = __expf(lrelu_att(ev.x + edv.x) - mx.x);
                ex.y = __expf(lrelu_att(ev.y + edv.y) - mx.y);
                ex.z = __expf(lrelu_att(ev.z + edv.z) - mx.z);
                ex.w = __expf(lrelu_att(ev.w + edv.w) - mx.w);
            }
            den.x += ex.x; den.y += ex.y; den.z += ex.z; den.w += ex.w;
            sbuf[grp][lane16] = s;
            *(float4*)&exbuf[grp][lane16][0] = ex;
            for (int i = 0; i < cn; ++i) {
                int si = sbuf[grp][i];
                float e = exbuf[grp][i][hq];
                float4 hv = *(const float4*)(h + si * 64 + lane16 * 4);
                accv.x = fmaf(e, hv.x, accv.x);
                accv.y = fmaf(e, hv.y, accv.y);
                accv.z = fmaf(e, hv.z, accv.z);
                accv.w = fmaf(e, hv.w, accv.w);
            }
        }
    }

#pragma unroll
    for (int o = 1; o < 16; o <<= 1) {
        den.x += __shfl_xor(den.x, o, 16);
        den.y += __shfl_xor(den.y, o, 16);
        den.z += __shfl_xor(den.z, o, 16);
        den.w += __shfl_xor(den.w, o, 16);
    }
    float d = hq == 0 ? den.x : hq == 1 ? den.y : hq == 2 ? den.z : den.w;
    float inv = 1.f / (d + 1e-16f);
    *(float4*)(agg + n * 64 + lane16 * 4) =
        make_float4(accv.x * inv, accv.y * inv, accv.z * inv, accv.w * inv);
}

// ---- BatchNorm statistics (sum, sumsq per channel), f64 accumulators ----
__global__ __launch_bounds__(256) void k_bn_reduce(const float* __restrict__ agg,
                                                   const float* __restrict__ bias,
                                                   double* __restrict__ bnsum) {
    const int j = threadIdx.x & 63, r = threadIdx.x >> 6;
    const float bj = bias[j];
    double ds = 0.0, ds2 = 0.0;
    const int total = NN * 64;
    const int stride = gridDim.x * blockDim.x;
    for (int idx = blockIdx.x * blockDim.x + threadIdx.x; idx < total; idx += stride) {
        float v = agg[idx] + bj;
        ds += v;
        ds2 += (double)v * v;
    }
    __shared__ double sh[2][4][64];
    sh[0][r][j] = ds;
    sh[1][r][j] = ds2;
    __syncthreads();
    if (r == 0) {
        double t1 = sh[0][0][j] + sh[0][1][j] + sh[0][2][j] + sh[0][3][j];
        double t2 = sh[1][0][j] + sh[1][1][j] + sh[1][2][j] + sh[1][3][j];
        atomicAdd(&bnsum[j], t1);
        atomicAdd(&bnsum[64 + j], t2);
    }
}

__global__ void k_bn_final(const double* __restrict__ bnsum,
                           const float* __restrict__ gamma,
                           const float* __restrict__ beta,
                           const float* __restrict__ bias,
                           float* __restrict__ ss) {
    int j = threadIdx.x;
    if (j < 64) {
        double mean = bnsum[j] / (double)NN;
        double var = bnsum[64 + j] / (double)NN - mean * mean;
        float sc = (float)(1.0 / sqrt(var + (double)EPS)) * gamma[j];
        ss[j] = sc;
        ss[64 + j] = beta[j] + (bias[j] - (float)mean) * sc;   // bias folded in
    }
}

// ---- norm + GraphSizeNorm + LeakyReLU + pool + residual (contiguous blocks) ----
constexpr int NA_BLOCKS = 512;
constexpr int NA_NODES = (NN + NA_BLOCKS - 1) / NA_BLOCKS;   // 196
__global__ __launch_bounds__(256) void k_norm_act(const float* __restrict__ agg,
                                                  const float* __restrict__ ss,
                                                  const int* __restrict__ batch,
                                                  const float* __restrict__ cnt,
                                                  float* __restrict__ xcur,
                                                  float* __restrict__ pool) {
    __shared__ float sp[GG * 64];
    for (int i = threadIdx.x; i < GG * 64; i += 256) sp[i] = 0.f;
    __syncthreads();
    const int j = threadIdx.x & 63, r = threadIdx.x >> 6;
    const float sc = ss[j], shf = ss[64 + j];
    const int n0 = blockIdx.x * NA_NODES;
    const int n1 = min(n0 + NA_NODES, NN);
    float racc = 0.f;
    int curg = -1;
    float rinv = 0.f;
    for (int n = n0 + r; n < n1; n += 4) {
        int g = batch[n];
        if (g != curg) {
            if (curg >= 0) atomicAdd(&sp[curg * 64 + j], racc);
            curg = g; racc = 0.f;
            rinv = rsqrtf(cnt[g]);
        }
        float v = (agg[n * 64 + j] * sc + shf) * rinv;
        v = v > 0.f ? v : SLOPE_ACT * v;
        racc += v;
        xcur[n * 64 + j] += v;
    }
    if (curg >= 0) atomicAdd(&sp[curg * 64 + j], racc);
    __syncthreads();
    for (int i = threadIdx.x; i < GG * 64; i += 256)
        if (sp[i] != 0.f) atomicAdd(&pool[i], sp[i]);
}

// ---- readout head ----
__global__ void k_head(const float* __restrict__ pools,
                       const float* __restrict__ cnt,
                       const float* __restrict__ Wr,
                       const float* __restrict__ br,
                       float* __restrict__ out) {
    __shared__ float risk[GG * NCLS];
    int t = threadIdx.x;
    if (t < GG * NCLS) {
        int g = t / NCLS, c = t % NCLS;
        float acc = br[c];
        float icnt = 1.f / cnt[g];
        for (int k = 0; k < (LL + 1) * DIM; ++k) {
            int l = k >> 6, j = k & 63;
            float xc = pools[(l * GG + g) * 64 + j] * icnt;
            acc += xc * Wr[k * NCLS + c];
        }
        risk[t] = acc;
        out[t] = acc;
    }
    __syncthreads();
    if (t < GG) {
        float r0 = risk[t * 2], r1 = risk[t * 2 + 1];
        float m = fmaxf(r0, r1);
        float e0 = expf(r0 - m), e1 = expf(r1 - m);
        float s = e0 + e1;
        out[GG * NCLS + t * 2] = e0 / s;
        out[GG * NCLS + t * 2 + 1] = e1 / s;
        out[2 * GG * NCLS + t] = (r1 > r0) ? 1.f : 0.f;
    }
}

extern "C" void kernel_launch(void* const* d_in, const int* in_sizes, int n_in,
                              void* d_out, int out_size, void* d_ws, size_t ws_size,
                              hipStream_t stream) {
    const float* x     = (const float*)d_in[0];
    const int*   ei    = (const int*)d_in[1];
    const int*   batch = (const int*)d_in[2];
    const float* W     = (const float*)d_in[4];
    const float* asrc  = (const float*)d_in[5];
    const float* adst  = (const float*)d_in[6];
    const float* bias  = (const float*)d_in[7];
    const float* gamma = (const float*)d_in[8];
    const float* beta  = (const float*)d_in[9];
    const float* Wr    = (const float*)d_in[10];
    const float* br    = (const float*)d_in[11];
    float* out = (float*)d_out;

    char* ws = (char*)d_ws;
    size_t off = 0;
    auto alloc = [&](size_t bytes) {
        void* p = ws + off;
        off += (bytes + 255) & ~(size_t)255;
        return p;
    };
    float* xcur      = (float*)alloc((size_t)NN * 64 * 4);
    float* h         = (float*)alloc((size_t)NN * 64 * 4);
    float* agg       = (float*)alloc((size_t)NN * 64 * 4);
    float* es        = (float*)alloc((size_t)NN * 4 * 4);
    float* ed        = (float*)alloc((size_t)NN * 4 * 4);
    int*   row_start = (int*)alloc((size_t)(NN + 1) * 4);
    int*   ssrc      = (int*)alloc((size_t)EE * 4);
    double* bnsum    = (double*)alloc(128 * 8);
    float* ss        = (float*)alloc(128 * 4);
    float* pools     = (float*)alloc((size_t)(LL + 1) * GG * 64 * 4);
    float* cnt       = (float*)alloc((size_t)GG * 4);
    (void)ws_size; (void)in_sizes; (void)n_in; (void)out_size;

    // CSR-build scratch aliases agg (dead until k_gat_agg overwrites it)
    int* deg     = (int*)agg;
    int* cursor  = (int*)agg + NN;
    int* bsum    = (int*)agg + 2 * NN;
    int* bsum_sc = (int*)agg + 2 * NN + 256;

    hipMemsetAsync(pools, 0, (size_t)(LL + 1) * GG * 64 * 4, stream);
    hipMemsetAsync(cnt, 0, (size_t)GG * 4, stream);
    hipMemsetAsync(deg, 0, (size_t)NN * 4, stream);

    // ---- build CSR (once; reused by all 3 layers) ----
    k_hist<<<(EE / 4 + 255) / 256, 256, 0, stream>>>(ei, deg);
    k_scan1<<<NSCAN, 256, 0, stream>>>(deg, row_start, bsum);
    k_scan2<<<1, 128, 0, stream>>>(bsum, bsum_sc);
    k_scan3<<<(NN + 255) / 256, 256, 0, stream>>>(row_start, bsum_sc, cursor);
    k_fill<<<8 * FILL_NBLK, 256, 0, stream>>>(ei, cursor, ssrc);

    k_pool0<<<2048, 256, 0, stream>>>(x, batch, pools, cnt, xcur);

    for (int l = 0; l < LL; ++l) {
        hipMemsetAsync(bnsum, 0, 128 * 8, stream);
        k_gemm<<<(NN + 63) / 64, 256, 0, stream>>>(xcur, W + l * DIM * DIM,
                                                   asrc + l * HH * CC, adst + l * HH * CC,
                                                   h, es, ed);
        k_gat_agg<<<NN / 16, 256, 0, stream>>>(row_start, ssrc, es, ed, h, agg);
        k_bn_reduce<<<1024, 256, 0, stream>>>(agg, bias + l * DIM, bnsum);
        k_bn_final<<<1, 64, 0, stream>>>(bnsum, gamma + l * DIM, beta + l * DIM,
                                         bias + l * DIM, ss);
        k_norm_act<<<NA_BLOCKS, 256, 0, stream>>>(agg, ss, batch, cnt,
                                                  xcur, pools + (size_t)(l + 1) * GG * 64);
    }

    k_head<<<1, 64, 0, stream>>>(pools, cnt, Wr, br, out);
}

// Round 5
// 738.746 us; speedup vs baseline: 4.7696x; 1.0265x over previous
//
#include <hip/hip_runtime.h>

// Problem constants (fixed by the reference)
constexpr int NN   = 100000;   // nodes
constexpr int EE   = 1600000;  // edges
constexpr int DIM  = 64;
constexpr int HH   = 4;        // heads
constexpr int CC   = 16;       // channels / head
constexpr int LL   = 3;        // layers
constexpr int GG   = 16;       // graphs
constexpr int NCLS = 2;
constexpr float SLOPE_ATT = 0.2f;
constexpr float SLOPE_ACT = 0.01f;
constexpr float EPS = 1e-5f;

constexpr int SCAN_CHUNK = 1024;
constexpr int NSCAN = (NN + SCAN_CHUNK - 1) / SCAN_CHUNK;   // 98

__device__ __forceinline__ float lrelu_att(float v) { return v > 0.f ? v : SLOPE_ATT * v; }

// bf16 round-to-nearest-even pack/unpack
__device__ __forceinline__ unsigned short f2bf(float f) {
    unsigned u = __float_as_uint(f);
    unsigned r = u + 0x7FFFu + ((u >> 16) & 1u);
    return (unsigned short)(r >> 16);
}
__device__ __forceinline__ float bf2f(unsigned short b) {
    return __uint_as_float(((unsigned)b) << 16);
}

// ---- pool of x0 + node counts per graph + xcur init (fused memcpy) ----
__global__ __launch_bounds__(256) void k_pool0(const float* __restrict__ x,
                                               const int* __restrict__ batch,
                                               float* __restrict__ pool0,
                                               float* __restrict__ cnt,
                                               float* __restrict__ xcur) {
    __shared__ float sp[GG * DIM];
    __shared__ float sc[GG];
    for (int i = threadIdx.x; i < GG * DIM; i += blockDim.x) sp[i] = 0.f;
    if (threadIdx.x < GG) sc[threadIdx.x] = 0.f;
    __syncthreads();
    const int total = NN * DIM;
    const int stride = gridDim.x * blockDim.x;
    for (int idx = blockIdx.x * blockDim.x + threadIdx.x; idx < total; idx += stride) {
        int n = idx >> 6, j = idx & 63;
        int g = batch[n];
        float v = x[idx];
        xcur[idx] = v;
        atomicAdd(&sp[g * DIM + j], v);
        if (j == 0) atomicAdd(&sc[g], 1.f);
    }
    __syncthreads();
    for (int i = threadIdx.x; i < GG * DIM; i += blockDim.x)
        if (sp[i] != 0.f) atomicAdd(&pool0[i], sp[i]);
    if (threadIdx.x < GG && sc[threadIdx.x] != 0.f) atomicAdd(&cnt[threadIdx.x], sc[threadIdx.x]);
}

// ---- CSR build: histogram of dst (int4 vectorized) ----
__global__ __launch_bounds__(256) void k_hist(const int* __restrict__ ei,
                                              int* __restrict__ deg) {
    int i = blockIdx.x * 256 + threadIdx.x;
    if (i < EE / 4) {
        int4 d = ((const int4*)(ei + EE))[i];
        atomicAdd(&deg[d.x], 1);
        atomicAdd(&deg[d.y], 1);
        atomicAdd(&deg[d.z], 1);
        atomicAdd(&deg[d.w], 1);
    }
}

// ---- scan step 1: per-chunk exclusive scan + chunk totals ----
__global__ __launch_bounds__(256) void k_scan1(const int* __restrict__ deg,
                                               int* __restrict__ excl,
                                               int* __restrict__ bsum) {
    __shared__ int sh[256];
    const int b = blockIdx.x, t = threadIdx.x;
    const int i0 = b * SCAN_CHUNK + t * 4;
    int v[4];
#pragma unroll
    for (int i = 0; i < 4; ++i) v[i] = (i0 + i < NN) ? deg[i0 + i] : 0;
    int tsum = v[0] + v[1] + v[2] + v[3];
    sh[t] = tsum;
    __syncthreads();
    for (int o = 1; o < 256; o <<= 1) {
        int x = (t >= o) ? sh[t - o] : 0;
        __syncthreads();
        sh[t] += x;
        __syncthreads();
    }
    if (t == 255) bsum[b] = sh[255];
    int run = sh[t] - tsum;
#pragma unroll
    for (int i = 0; i < 4; ++i) {
        if (i0 + i < NN) excl[i0 + i] = run;
        run += v[i];
    }
}

// ---- scan step 2: exclusive scan of chunk totals (1 block) ----
__global__ void k_scan2(const int* __restrict__ bsum, int* __restrict__ bsum_sc) {
    __shared__ int sh[128];
    const int t = threadIdx.x;
    const int own = (t < NSCAN) ? bsum[t] : 0;
    sh[t] = own;
    __syncthreads();
    for (int o = 1; o < 128; o <<= 1) {
        int x = (t >= o) ? sh[t - o] : 0;
        __syncthreads();
        sh[t] += x;
        __syncthreads();
    }
    if (t < NSCAN) bsum_sc[t] = sh[t] - own;
}

// ---- scan step 3: add chunk offsets, write cursor copy, set sentinel ----
__global__ __launch_bounds__(256) void k_scan3(int* __restrict__ row_start,
                                               const int* __restrict__ bsum_sc,
                                               int* __restrict__ cursor) {
    int i = blockIdx.x * 256 + threadIdx.x;
    if (i < NN) {
        int v = row_start[i] + bsum_sc[i / SCAN_CHUNK];
        row_start[i] = v;
        cursor[i] = v;
    }
    if (i == 0) row_start[NN] = EE;
}

// ---- CSR fill, XCD-range partitioned ----
constexpr int FILL_NBLK = 256;
constexpr int DRANGE = (NN + 7) / 8;
__global__ __launch_bounds__(256) void k_fill(const int* __restrict__ ei,
                                              int* __restrict__ cursor,
                                              int* __restrict__ ssrc) {
    const int g = blockIdx.x & 7;
    const int blk = blockIdx.x >> 3;
    const int dlo = g * DRANGE, dhi = min(dlo + DRANGE, NN);
    const int stride = FILL_NBLK * 256;
    for (int e = blk * 256 + threadIdx.x; e < EE; e += stride) {
        int d = ei[EE + e];
        if (d >= dlo && d < dhi) {
            int s = ei[e];
            int pos = atomicAdd(&cursor[d], 1);
            ssrc[pos] = s;
        }
    }
}

// ---- h = x @ W (bf16 out), 4x4 register tiling, XOR-swizzled x^T tile ----
// block 0 also zeroes the BN replica accumulators for this layer.
__global__ __launch_bounds__(256) void k_gemm(const float* __restrict__ xin,
                                              const float* __restrict__ Wl,
                                              const float* __restrict__ asrc,
                                              const float* __restrict__ adst,
                                              unsigned short* __restrict__ h,
                                              float* __restrict__ es,
                                              float* __restrict__ ed,
                                              double* __restrict__ bnrep) {
    if (blockIdx.x == 0) {
#pragma unroll
        for (int i = 0; i < 4; ++i) bnrep[threadIdx.x + 256 * i] = 0.0;
    }
    __shared__ float Ws[DIM][DIM];
    __shared__ float xsT[DIM][DIM];
    const int tid = threadIdx.x;
    const int row0 = blockIdx.x * 64;

    const float4* W4 = (const float4*)Wl;
#pragma unroll
    for (int i = 0; i < 4; ++i) ((float4*)Ws)[tid + 256 * i] = W4[tid + 256 * i];

#pragma unroll
    for (int i = 0; i < 4; ++i) {
        int idx4 = tid + 256 * i;
        int r = idx4 >> 4, c4 = idx4 & 15;
        int grow = row0 + r;
        float4 v = make_float4(0.f, 0.f, 0.f, 0.f);
        if (grow < NN) v = ((const float4*)xin)[grow * 16 + c4];
        int col = (((r >> 2) ^ c4) << 2) | (r & 3);
        xsT[c4 * 4 + 0][col] = v.x;
        xsT[c4 * 4 + 1][col] = v.y;
        xsT[c4 * 4 + 2][col] = v.z;
        xsT[c4 * 4 + 3][col] = v.w;
    }
    __syncthreads();

    const int tc = tid & 15, tr = tid >> 4;
    float acc[4][4] = {};
#pragma unroll 8
    for (int k = 0; k < DIM; ++k) {
        int kc = (k >> 2) & 15;
        float4 wv = *(const float4*)(&Ws[k][tc * 4]);
        float4 xv = *(const float4*)(&xsT[k][(tr ^ kc) * 4]);
        acc[0][0] = fmaf(xv.x, wv.x, acc[0][0]);
        acc[0][1] = fmaf(xv.x, wv.y, acc[0][1]);
        acc[0][2] = fmaf(xv.x, wv.z, acc[0][2]);
        acc[0][3] = fmaf(xv.x, wv.w, acc[0][3]);
        acc[1][0] = fmaf(xv.y, wv.x, acc[1][0]);
        acc[1][1] = fmaf(xv.y, wv.y, acc[1][1]);
        acc[1][2] = fmaf(xv.y, wv.z, acc[1][2]);
        acc[1][3] = fmaf(xv.y, wv.w, acc[1][3]);
        acc[2][0] = fmaf(xv.z, wv.x, acc[2][0]);
        acc[2][1] = fmaf(xv.z, wv.y, acc[2][1]);
        acc[2][2] = fmaf(xv.z, wv.z, acc[2][2]);
        acc[2][3] = fmaf(xv.z, wv.w, acc[2][3]);
        acc[3][0] = fmaf(xv.w, wv.x, acc[3][0]);
        acc[3][1] = fmaf(xv.w, wv.y, acc[3][1]);
        acc[3][2] = fmaf(xv.w, wv.z, acc[3][2]);
        acc[3][3] = fmaf(xv.w, wv.w, acc[3][3]);
    }

    float a_s[4], a_d[4];
#pragma unroll
    for (int c = 0; c < 4; ++c) { a_s[c] = asrc[4 * tc + c]; a_d[c] = adst[4 * tc + c]; }

#pragma unroll
    for (int r = 0; r < 4; ++r) {
        int n = row0 + 4 * tr + r;
        if (n < NN) {
            ushort4 hb;
            hb.x = f2bf(acc[r][0]); hb.y = f2bf(acc[r][1]);
            hb.z = f2bf(acc[r][2]); hb.w = f2bf(acc[r][3]);
            *(ushort4*)(h + n * 64 + 4 * tc) = hb;
            float ps = acc[r][0] * a_s[0] + acc[r][1] * a_s[1] +
                       acc[r][2] * a_s[2] + acc[r][3] * a_s[3];
            float pd = acc[r][0] * a_d[0] + acc[r][1] * a_d[1] +
                       acc[r][2] * a_d[2] + acc[r][3] * a_d[3];
            ps += __shfl_xor(ps, 1); ps += __shfl_xor(ps, 2);
            pd += __shfl_xor(pd, 1); pd += __shfl_xor(pd, 2);
            if ((tc & 3) == 0) {
                es[n * 4 + (tc >> 2)] = ps;
                ed[n * 4 + (tc >> 2)] = pd;
            }
        }
    }
}

// ---- fused GAT aggregation + BN statistics ----
// 16-lane group per dst node, 16 nodes/block; h gathered as bf16.
// Epilogue: block-level channel sums/sumsq -> 8-replica f64 atomics.
__global__ __launch_bounds__(256) void k_gat_agg(const int* __restrict__ row_start,
                                                 const int* __restrict__ ssrc,
                                                 const float* __restrict__ es,
                                                 const float* __restrict__ ed,
                                                 const unsigned short* __restrict__ h,
                                                 float* __restrict__ agg,
                                                 double* __restrict__ bnrep) {
    __shared__ int   sbuf[16][33];
    __shared__ float exbuf[16][33][4];
    __shared__ float st[128];            // [0..63] sum, [64..127] sumsq
    if (threadIdx.x < 128) st[threadIdx.x] = 0.f;
    __syncthreads();

    const int lane16 = threadIdx.x & 15;
    const int grp    = threadIdx.x >> 4;
    const int n = blockIdx.x * 16 + grp;            // NN % 16 == 0
    const int base = row_start[n];
    const int deg  = row_start[n + 1] - base;
    const float4 edv = *(const float4*)(ed + n * 4);
    const int hq = lane16 >> 2;
    const ushort4* h4 = (const ushort4*)h;          // row = 16 x ushort4

    float4 accv = make_float4(0.f, 0.f, 0.f, 0.f);
    float4 den  = make_float4(0.f, 0.f, 0.f, 0.f);

    if (deg <= 32) {
        int s0 = 0, s1 = 0;
        float4 al0 = make_float4(-INFINITY, -INFINITY, -INFINITY, -INFINITY);
        float4 al1 = al0;
        if (lane16 < deg) {
            s0 = ssrc[base + lane16];
            float4 ev = *(const float4*)(es + s0 * 4);
            al0.x = lrelu_att(ev.x + edv.x); al0.y = lrelu_att(ev.y + edv.y);
            al0.z = lrelu_att(ev.z + edv.z); al0.w = lrelu_att(ev.w + edv.w);
        }
        if (lane16 + 16 < deg) {
            s1 = ssrc[base + 16 + lane16];
            float4 ev = *(const float4*)(es + s1 * 4);
            al1.x = lrelu_att(ev.x + edv.x); al1.y = lrelu_att(ev.y + edv.y);
            al1.z = lrelu_att(ev.z + edv.z); al1.w = lrelu_att(ev.w + edv.w);
        }
        float4 mx = make_float4(fmaxf(al0.x, al1.x), fmaxf(al0.y, al1.y),
                                fmaxf(al0.z, al1.z), fmaxf(al0.w, al1.w));
#pragma unroll
        for (int o = 1; o < 16; o <<= 1) {
            mx.x = fmaxf(mx.x, __shfl_xor(mx.x, o, 16));
            mx.y = fmaxf(mx.y, __shfl_xor(mx.y, o, 16));
            mx.z = fmaxf(mx.z, __shfl_xor(mx.z, o, 16));
            mx.w = fmaxf(mx.w, __shfl_xor(mx.w, o, 16));
        }
        float4 ex0 = make_float4(0.f, 0.f, 0.f, 0.f), ex1 = ex0;
        if (lane16 < deg) {
            ex0.x = __expf(al0.x - mx.x); ex0.y = __expf(al0.y - mx.y);
            ex0.z = __expf(al0.z - mx.z); ex0.w = __expf(al0.w - mx.w);
        }
        if (lane16 + 16 < deg) {
            ex1.x = __expf(al1.x - mx.x); ex1.y = __expf(al1.y - mx.y);
            ex1.z = __expf(al1.z - mx.z); ex1.w = __expf(al1.w - mx.w);
        }
        den.x = ex0.x + ex1.x; den.y = ex0.y + ex1.y;
        den.z = ex0.z + ex1.z; den.w = ex0.w + ex1.w;
        sbuf[grp][lane16] = s0;
        sbuf[grp][lane16 + 16] = s1;
        *(float4*)&exbuf[grp][lane16][0] = ex0;
        *(float4*)&exbuf[grp][lane16 + 16][0] = ex1;
        // wave-coherent LDS within 16-lane group: no barrier needed
#pragma unroll 4
        for (int i = 0; i < deg; ++i) {
            int si = sbuf[grp][i];
            float e = exbuf[grp][i][hq];
            ushort4 hv4 = h4[si * 16 + lane16];
            accv.x = fmaf(e, bf2f(hv4.x), accv.x);
            accv.y = fmaf(e, bf2f(hv4.y), accv.y);
            accv.z = fmaf(e, bf2f(hv4.z), accv.z);
            accv.w = fmaf(e, bf2f(hv4.w), accv.w);
        }
    } else {
        float4 mx = make_float4(-INFINITY, -INFINITY, -INFINITY, -INFINITY);
        for (int c0 = 0; c0 < deg; c0 += 16) {
            if (c0 + lane16 < deg) {
                int s = ssrc[base + c0 + lane16];
                float4 ev = *(const float4*)(es + s * 4);
                mx.x = fmaxf(mx.x, lrelu_att(ev.x + edv.x));
                mx.y = fmaxf(mx.y, lrelu_att(ev.y + edv.y));
                mx.z = fmaxf(mx.z, lrelu_att(ev.z + edv.z));
                mx.w = fmaxf(mx.w, lrelu_att(ev.w + edv.w));
            }
        }
#pragma unroll
        for (int o = 1; o < 16; o <<= 1) {
            mx.x = fmaxf(mx.x, __shfl_xor(mx.x, o, 16));
            mx.y = fmaxf(mx.y, __shfl_xor(mx.y, o, 16));
            mx.z = fmaxf(mx.z, __shfl_xor(mx.z, o, 16));
            mx.w = fmaxf(mx.w, __shfl_xor(mx.w, o, 16));
        }
        for (int c0 = 0; c0 < deg; c0 += 16) {
            int cn = min(16, deg - c0);
            float4 ex = make_float4(0.f, 0.f, 0.f, 0.f);
            int s = 0;
            if (lane16 < cn) {
                s = ssrc[base + c0 + lane16];
                float4 ev = *(const float4*)(es + s * 4);
                ex.x = __expf(lrelu_att(ev.x + edv.x) - mx.x);
                ex.y = __expf(lrelu_att(ev.y + edv.y) - mx.y);
                ex.z = __expf(lrelu_att(ev.z + edv.z) - mx.z);
                ex.w = __expf(lrelu_att(ev.w + edv.w) - mx.w);
            }
            den.x += ex.x; den.y += ex.y; den.z += ex.z; den.w += ex.w;
            sbuf[grp][lane16] = s;
            *(float4*)&exbuf[grp][lane16][0] = ex;
            for (int i = 0; i < cn; ++i) {
                int si = sbuf[grp][i];
                float e = exbuf[grp][i][hq];
                ushort4 hv4 = h4[si * 16 + lane16];
                accv.x = fmaf(e, bf2f(hv4.x), accv.x);
                accv.y = fmaf(e, bf2f(hv4.y), accv.y);
                accv.z = fmaf(e, bf2f(hv4.z), accv.z);
                accv.w = fmaf(e, bf2f(hv4.w), accv.w);
            }
        }
    }

#pragma unroll
    for (int o = 1; o < 16; o <<= 1) {
        den.x += __shfl_xor(den.x, o, 16);
        den.y += __shfl_xor(den.y, o, 16);
        den.z += __shfl_xor(den.z, o, 16);
        den.w += __shfl_xor(den.w, o, 16);
    }
    float d = hq == 0 ? den.x : hq == 1 ? den.y : hq == 2 ? den.z : den.w;
    float inv = 1.f / (d + 1e-16f);
    float4 o4 = make_float4(accv.x * inv, accv.y * inv, accv.z * inv, accv.w * inv);
    *(float4*)(agg + n * 64 + lane16 * 4) = o4;

    // ---- BN stats epilogue (uniform control flow) ----
    const int c0 = lane16 * 4;
    atomicAdd(&st[c0 + 0], o4.x);
    atomicAdd(&st[c0 + 1], o4.y);
    atomicAdd(&st[c0 + 2], o4.z);
    atomicAdd(&st[c0 + 3], o4.w);
    atomicAdd(&st[64 + c0 + 0], o4.x * o4.x);
    atomicAdd(&st[64 + c0 + 1], o4.y * o4.y);
    atomicAdd(&st[64 + c0 + 2], o4.z * o4.z);
    atomicAdd(&st[64 + c0 + 3], o4.w * o4.w);
    __syncthreads();
    if (threadIdx.x < 64) {
        double* rep = bnrep + (blockIdx.x & 7) * 128;
        atomicAdd(&rep[threadIdx.x], (double)st[threadIdx.x]);
        atomicAdd(&rep[64 + threadIdx.x], (double)st[64 + threadIdx.x]);
    }
}

// ---- norm + GraphSizeNorm + LeakyReLU + pool + residual ----
// BN scale/shift derived in-kernel from the 8-replica f64 stats.
constexpr int NA_BLOCKS = 512;
constexpr int NA_NODES = (NN + NA_BLOCKS - 1) / NA_BLOCKS;   // 196
__global__ __launch_bounds__(256) void k_norm_act(const float* __restrict__ agg,
                                                  const double* __restrict__ bnrep,
                                                  const float* __restrict__ gamma,
                                                  const float* __restrict__ beta,
                                                  const int* __restrict__ batch,
                                                  const float* __restrict__ cnt,
                                                  float* __restrict__ xcur,
                                                  float* __restrict__ pool) {
    __shared__ float sp[GG * 64];
    for (int i = threadIdx.x; i < GG * 64; i += 256) sp[i] = 0.f;
    __syncthreads();
    const int j = threadIdx.x & 63, r = threadIdx.x >> 6;
    double s1 = 0.0, s2 = 0.0;
#pragma unroll
    for (int rp = 0; rp < 8; ++rp) {
        s1 += bnrep[rp * 128 + j];
        s2 += bnrep[rp * 128 + 64 + j];
    }
    double mean = s1 / (double)NN;
    double var = s2 / (double)NN - mean * mean;
    const float sc = (float)(1.0 / sqrt(var + (double)EPS)) * gamma[j];
    const float shf = beta[j] - (float)mean * sc;

    const int n0 = blockIdx.x * NA_NODES;
    const int n1 = min(n0 + NA_NODES, NN);
    float racc = 0.f;
    int curg = -1;
    float rinv = 0.f;
    for (int n = n0 + r; n < n1; n += 4) {
        int g = batch[n];
        if (g != curg) {
            if (curg >= 0) atomicAdd(&sp[curg * 64 + j], racc);
            curg = g; racc = 0.f;
            rinv = rsqrtf(cnt[g]);
        }
        float v = (agg[n * 64 + j] * sc + shf) * rinv;
        v = v > 0.f ? v : SLOPE_ACT * v;
        racc += v;
        xcur[n * 64 + j] += v;
    }
    if (curg >= 0) atomicAdd(&sp[curg * 64 + j], racc);
    __syncthreads();
    for (int i = threadIdx.x; i < GG * 64; i += 256)
        if (sp[i] != 0.f) atomicAdd(&pool[i], sp[i]);
}

// ---- readout head ----
__global__ void k_head(const float* __restrict__ pools,
                       const float* __restrict__ cnt,
                       const float* __restrict__ Wr,
                       const float* __restrict__ br,
                       float* __restrict__ out) {
    __shared__ float risk[GG * NCLS];
    int t = threadIdx.x;
    if (t < GG * NCLS) {
        int g = t / NCLS, c = t % NCLS;
        float acc = br[c];
        float icnt = 1.f / cnt[g];
        for (int k = 0; k < (LL + 1) * DIM; ++k) {
            int l = k >> 6, j = k & 63;
            float xc = pools[(l * GG + g) * 64 + j] * icnt;
            acc += xc * Wr[k * NCLS + c];
        }
        risk[t] = acc;
        out[t] = acc;
    }
    __syncthreads();
    if (t < GG) {
        float r0 = risk[t * 2], r1 = risk[t * 2 + 1];
        float m = fmaxf(r0, r1);
        float e0 = expf(r0 - m), e1 = expf(r1 - m);
        float s = e0 + e1;
        out[GG * NCLS + t * 2] = e0 / s;
        out[GG * NCLS + t * 2 + 1] = e1 / s;
        out[2 * GG * NCLS + t] = (r1 > r0) ? 1.f : 0.f;
    }
}

extern "C" void kernel_launch(void* const* d_in, const int* in_sizes, int n_in,
                              void* d_out, int out_size, void* d_ws, size_t ws_size,
                              hipStream_t stream) {
    const float* x     = (const float*)d_in[0];
    const int*   ei    = (const int*)d_in[1];
    const int*   batch = (const int*)d_in[2];
    const float* W     = (const float*)d_in[4];
    const float* asrc  = (const float*)d_in[5];
    const float* adst  = (const float*)d_in[6];
    const float* gamma = (const float*)d_in[8];
    const float* beta  = (const float*)d_in[9];
    const float* Wr    = (const float*)d_in[10];
    const float* br    = (const float*)d_in[11];
    float* out = (float*)d_out;

    char* ws = (char*)d_ws;
    size_t off = 0;
    auto alloc = [&](size_t bytes) {
        void* p = ws + off;
        off += (bytes + 255) & ~(size_t)255;
        return p;
    };
    float*          xcur      = (float*)alloc((size_t)NN * 64 * 4);
    unsigned short* h         = (unsigned short*)alloc((size_t)NN * 64 * 2);
    float*          agg       = (float*)alloc((size_t)NN * 64 * 4);
    float*          es        = (float*)alloc((size_t)NN * 4 * 4);
    float*          ed        = (float*)alloc((size_t)NN * 4 * 4);
    int*            row_start = (int*)alloc((size_t)(NN + 1) * 4);
    int*            ssrc      = (int*)alloc((size_t)EE * 4);
    double*         bnrep     = (double*)alloc(8 * 128 * 8);
    float*          pools     = (float*)alloc((size_t)(LL + 1) * GG * 64 * 4);
    float*          cnt       = (float*)alloc((size_t)GG * 4);
    (void)ws_size; (void)in_sizes; (void)n_in; (void)out_size;

    // CSR-build scratch aliases agg (dead until k_gat_agg overwrites it)
    int* deg     = (int*)agg;
    int* cursor  = (int*)agg + NN;
    int* bsum    = (int*)agg + 2 * NN;
    int* bsum_sc = (int*)agg + 2 * NN + 256;

    hipMemsetAsync(pools, 0, (size_t)(LL + 1) * GG * 64 * 4, stream);
    hipMemsetAsync(cnt, 0, (size_t)GG * 4, stream);
    hipMemsetAsync(deg, 0, (size_t)NN * 4, stream);

    // ---- build CSR (once; reused by all 3 layers) ----
    k_hist<<<(EE / 4 + 255) / 256, 256, 0, stream>>>(ei, deg);
    k_scan1<<<NSCAN, 256, 0, stream>>>(deg, row_start, bsum);
    k_scan2<<<1, 128, 0, stream>>>(bsum, bsum_sc);
    k_scan3<<<(NN + 255) / 256, 256, 0, stream>>>(row_start, bsum_sc, cursor);
    k_fill<<<8 * FILL_NBLK, 256, 0, stream>>>(ei, cursor, ssrc);

    k_pool0<<<2048, 256, 0, stream>>>(x, batch, pools, cnt, xcur);

    for (int l = 0; l < LL; ++l) {
        k_gemm<<<(NN + 63) / 64, 256, 0, stream>>>(xcur, W + l * DIM * DIM,
                                                   asrc + l * HH * CC, adst + l * HH * CC,
                                                   h, es, ed, bnrep);
        k_gat_agg<<<NN / 16, 256, 0, stream>>>(row_start, ssrc, es, ed, h, agg, bnrep);
        k_norm_act<<<NA_BLOCKS, 256, 0, stream>>>(agg, bnrep, gamma + l * DIM,
                                                  beta + l * DIM, batch, cnt,
                                                  xcur, pools + (size_t)(l + 1) * GG * 64);
    }

    k_head<<<1, 64, 0, stream>>>(pools, cnt, Wr, br, out);
}

// Round 6
// 614.573 us; speedup vs baseline: 5.7333x; 1.2020x over previous
//
#include <hip/hip_runtime.h>

// Problem constants (fixed by the reference)
constexpr int NN   = 100000;   // nodes
constexpr int EE   = 1600000;  // edges
constexpr int DIM  = 64;
constexpr int HH   = 4;        // heads
constexpr int CC   = 16;       // channels / head
constexpr int LL   = 3;        // layers
constexpr int GG   = 16;       // graphs
constexpr int NCLS = 2;
constexpr float SLOPE_ATT = 0.2f;
constexpr float SLOPE_ACT = 0.01f;
constexpr float EPS = 1e-5f;

constexpr int SCAN_CHUNK = 1024;
constexpr int NSCAN = (NN + SCAN_CHUNK - 1) / SCAN_CHUNK;   // 98
constexpr int NREP = 64;                                    // BN stat replicas

__device__ __forceinline__ float lrelu_att(float v) { return v > 0.f ? v : SLOPE_ATT * v; }

// bf16 helpers
__device__ __forceinline__ unsigned short f2bf(float f) {
    unsigned u = __float_as_uint(f);
    unsigned r = u + 0x7FFFu + ((u >> 16) & 1u);
    return (unsigned short)(r >> 16);
}
__device__ __forceinline__ float bflo(unsigned u) { return __uint_as_float(u << 16); }
__device__ __forceinline__ float bfhi(unsigned u) { return __uint_as_float(u & 0xFFFF0000u); }

// ---- pool of x0 + node counts per graph + xcur init (fused memcpy) ----
__global__ __launch_bounds__(256) void k_pool0(const float* __restrict__ x,
                                               const int* __restrict__ batch,
                                               float* __restrict__ pool0,
                                               float* __restrict__ cnt,
                                               float* __restrict__ xcur) {
    __shared__ float sp[GG * DIM];
    __shared__ float sc[GG];
    for (int i = threadIdx.x; i < GG * DIM; i += blockDim.x) sp[i] = 0.f;
    if (threadIdx.x < GG) sc[threadIdx.x] = 0.f;
    __syncthreads();
    const int total = NN * DIM;
    const int stride = gridDim.x * blockDim.x;
    for (int idx = blockIdx.x * blockDim.x + threadIdx.x; idx < total; idx += stride) {
        int n = idx >> 6, j = idx & 63;
        int g = batch[n];
        float v = x[idx];
        xcur[idx] = v;
        atomicAdd(&sp[g * DIM + j], v);
        if (j == 0) atomicAdd(&sc[g], 1.f);
    }
    __syncthreads();
    for (int i = threadIdx.x; i < GG * DIM; i += blockDim.x)
        if (sp[i] != 0.f) atomicAdd(&pool0[i], sp[i]);
    if (threadIdx.x < GG && sc[threadIdx.x] != 0.f) atomicAdd(&cnt[threadIdx.x], sc[threadIdx.x]);
}

// ---- CSR build: histogram of dst (int4 vectorized) ----
__global__ __launch_bounds__(256) void k_hist(const int* __restrict__ ei,
                                              int* __restrict__ deg) {
    int i = blockIdx.x * 256 + threadIdx.x;
    if (i < EE / 4) {
        int4 d = ((const int4*)(ei + EE))[i];
        atomicAdd(&deg[d.x], 1);
        atomicAdd(&deg[d.y], 1);
        atomicAdd(&deg[d.z], 1);
        atomicAdd(&deg[d.w], 1);
    }
}

// ---- scan step 1 ----
__global__ __launch_bounds__(256) void k_scan1(const int* __restrict__ deg,
                                               int* __restrict__ excl,
                                               int* __restrict__ bsum) {
    __shared__ int sh[256];
    const int b = blockIdx.x, t = threadIdx.x;
    const int i0 = b * SCAN_CHUNK + t * 4;
    int v[4];
#pragma unroll
    for (int i = 0; i < 4; ++i) v[i] = (i0 + i < NN) ? deg[i0 + i] : 0;
    int tsum = v[0] + v[1] + v[2] + v[3];
    sh[t] = tsum;
    __syncthreads();
    for (int o = 1; o < 256; o <<= 1) {
        int x = (t >= o) ? sh[t - o] : 0;
        __syncthreads();
        sh[t] += x;
        __syncthreads();
    }
    if (t == 255) bsum[b] = sh[255];
    int run = sh[t] - tsum;
#pragma unroll
    for (int i = 0; i < 4; ++i) {
        if (i0 + i < NN) excl[i0 + i] = run;
        run += v[i];
    }
}

// ---- scan step 2 ----
__global__ void k_scan2(const int* __restrict__ bsum, int* __restrict__ bsum_sc) {
    __shared__ int sh[128];
    const int t = threadIdx.x;
    const int own = (t < NSCAN) ? bsum[t] : 0;
    sh[t] = own;
    __syncthreads();
    for (int o = 1; o < 128; o <<= 1) {
        int x = (t >= o) ? sh[t - o] : 0;
        __syncthreads();
        sh[t] += x;
        __syncthreads();
    }
    if (t < NSCAN) bsum_sc[t] = sh[t] - own;
}

// ---- scan step 3 ----
__global__ __launch_bounds__(256) void k_scan3(int* __restrict__ row_start,
                                               const int* __restrict__ bsum_sc,
                                               int* __restrict__ cursor) {
    int i = blockIdx.x * 256 + threadIdx.x;
    if (i < NN) {
        int v = row_start[i] + bsum_sc[i / SCAN_CHUNK];
        row_start[i] = v;
        cursor[i] = v;
    }
    if (i == 0) row_start[NN] = EE;
}

// ---- CSR fill, XCD-range partitioned ----
constexpr int FILL_NBLK = 256;
constexpr int DRANGE = (NN + 7) / 8;
__global__ __launch_bounds__(256) void k_fill(const int* __restrict__ ei,
                                              int* __restrict__ cursor,
                                              int* __restrict__ ssrc) {
    const int g = blockIdx.x & 7;
    const int blk = blockIdx.x >> 3;
    const int dlo = g * DRANGE, dhi = min(dlo + DRANGE, NN);
    const int stride = FILL_NBLK * 256;
    for (int e = blk * 256 + threadIdx.x; e < EE; e += stride) {
        int d = ei[EE + e];
        if (d >= dlo && d < dhi) {
            int s = ei[e];
            int pos = atomicAdd(&cursor[d], 1);
            ssrc[pos] = s;
        }
    }
}

// ---- h = x @ W (bf16 out), 4x4 register tiling, XOR-swizzled x^T tile ----
// blocks 0..63 zero their BN replica for this layer.
__global__ __launch_bounds__(256) void k_gemm(const float* __restrict__ xin,
                                              const float* __restrict__ Wl,
                                              const float* __restrict__ asrc,
                                              const float* __restrict__ adst,
                                              unsigned short* __restrict__ h,
                                              float* __restrict__ es,
                                              float* __restrict__ ed,
                                              double* __restrict__ bnrep) {
    if (blockIdx.x < NREP && threadIdx.x < 128)
        bnrep[(size_t)blockIdx.x * 128 + threadIdx.x] = 0.0;
    __shared__ float Ws[DIM][DIM];
    __shared__ float xsT[DIM][DIM];
    const int tid = threadIdx.x;
    const int row0 = blockIdx.x * 64;

    const float4* W4 = (const float4*)Wl;
#pragma unroll
    for (int i = 0; i < 4; ++i) ((float4*)Ws)[tid + 256 * i] = W4[tid + 256 * i];

#pragma unroll
    for (int i = 0; i < 4; ++i) {
        int idx4 = tid + 256 * i;
        int r = idx4 >> 4, c4 = idx4 & 15;
        int grow = row0 + r;
        float4 v = make_float4(0.f, 0.f, 0.f, 0.f);
        if (grow < NN) v = ((const float4*)xin)[grow * 16 + c4];
        int col = (((r >> 2) ^ c4) << 2) | (r & 3);
        xsT[c4 * 4 + 0][col] = v.x;
        xsT[c4 * 4 + 1][col] = v.y;
        xsT[c4 * 4 + 2][col] = v.z;
        xsT[c4 * 4 + 3][col] = v.w;
    }
    __syncthreads();

    const int tc = tid & 15, tr = tid >> 4;
    float acc[4][4] = {};
#pragma unroll 8
    for (int k = 0; k < DIM; ++k) {
        int kc = (k >> 2) & 15;
        float4 wv = *(const float4*)(&Ws[k][tc * 4]);
        float4 xv = *(const float4*)(&xsT[k][(tr ^ kc) * 4]);
        acc[0][0] = fmaf(xv.x, wv.x, acc[0][0]);
        acc[0][1] = fmaf(xv.x, wv.y, acc[0][1]);
        acc[0][2] = fmaf(xv.x, wv.z, acc[0][2]);
        acc[0][3] = fmaf(xv.x, wv.w, acc[0][3]);
        acc[1][0] = fmaf(xv.y, wv.x, acc[1][0]);
        acc[1][1] = fmaf(xv.y, wv.y, acc[1][1]);
        acc[1][2] = fmaf(xv.y, wv.z, acc[1][2]);
        acc[1][3] = fmaf(xv.y, wv.w, acc[1][3]);
        acc[2][0] = fmaf(xv.z, wv.x, acc[2][0]);
        acc[2][1] = fmaf(xv.z, wv.y, acc[2][1]);
        acc[2][2] = fmaf(xv.z, wv.z, acc[2][2]);
        acc[2][3] = fmaf(xv.z, wv.w, acc[2][3]);
        acc[3][0] = fmaf(xv.w, wv.x, acc[3][0]);
        acc[3][1] = fmaf(xv.w, wv.y, acc[3][1]);
        acc[3][2] = fmaf(xv.w, wv.z, acc[3][2]);
        acc[3][3] = fmaf(xv.w, wv.w, acc[3][3]);
    }

    float a_s[4], a_d[4];
#pragma unroll
    for (int c = 0; c < 4; ++c) { a_s[c] = asrc[4 * tc + c]; a_d[c] = adst[4 * tc + c]; }

#pragma unroll
    for (int r = 0; r < 4; ++r) {
        int n = row0 + 4 * tr + r;
        if (n < NN) {
            ushort4 hb;
            hb.x = f2bf(acc[r][0]); hb.y = f2bf(acc[r][1]);
            hb.z = f2bf(acc[r][2]); hb.w = f2bf(acc[r][3]);
            *(ushort4*)(h + n * 64 + 4 * tc) = hb;
            float ps = acc[r][0] * a_s[0] + acc[r][1] * a_s[1] +
                       acc[r][2] * a_s[2] + acc[r][3] * a_s[3];
            float pd = acc[r][0] * a_d[0] + acc[r][1] * a_d[1] +
                       acc[r][2] * a_d[2] + acc[r][3] * a_d[3];
            ps += __shfl_xor(ps, 1); ps += __shfl_xor(ps, 2);
            pd += __shfl_xor(pd, 1); pd += __shfl_xor(pd, 2);
            if ((tc & 3) == 0) {
                es[n * 4 + (tc >> 2)] = ps;
                ed[n * 4 + (tc >> 2)] = pd;
            }
        }
    }
}

// ---- fused GAT aggregation + BN statistics ----
// 16-lane group per dst node; inner gather = 2 edges/iter, 8 lanes x uint4
// (16B) each -> one wave instr moves 8 rows x 128B = 1KB coalesced.
__global__ __launch_bounds__(256) void k_gat_agg(const int* __restrict__ row_start,
                                                 const int* __restrict__ ssrc,
                                                 const float* __restrict__ es,
                                                 const float* __restrict__ ed,
                                                 const unsigned short* __restrict__ h,
                                                 float* __restrict__ agg,
                                                 double* __restrict__ bnrep) {
    __shared__ int   sbuf[16][34];
    __shared__ float exbuf[16][34][4];
    __shared__ float stS[4][64];
    __shared__ float stQ[4][64];

    const int lane16 = threadIdx.x & 15;
    const int grp    = threadIdx.x >> 4;   // 0..15
    const int wid    = threadIdx.x >> 6;   // 0..3
    const int sub    = lane16 >> 3;        // which edge of the pair
    const int l8     = lane16 & 7;         // channel-octet owner
    const int hq8    = l8 >> 1;            // head of channels 8*l8..8*l8+7
    const int n = blockIdx.x * 16 + grp;   // NN % 16 == 0
    const int base = row_start[n];
    const int deg  = row_start[n + 1] - base;
    const float4 edv = *(const float4*)(ed + n * 4);
    const uint4* h16 = (const uint4*)h;    // row = 8 x uint4 (128B)

    float acc8[8] = {};
    float4 denp = make_float4(0.f, 0.f, 0.f, 0.f);   // per-lane den partial

    if (deg <= 32) {
        // ---- fast path: single chunk ----
        int s0 = 0, s1 = 0;
        float4 al0 = make_float4(-INFINITY, -INFINITY, -INFINITY, -INFINITY);
        float4 al1 = al0;
        if (lane16 < deg) {
            s0 = ssrc[base + lane16];
            float4 ev = *(const float4*)(es + s0 * 4);
            al0.x = lrelu_att(ev.x + edv.x); al0.y = lrelu_att(ev.y + edv.y);
            al0.z = lrelu_att(ev.z + edv.z); al0.w = lrelu_att(ev.w + edv.w);
        }
        if (lane16 + 16 < deg) {
            s1 = ssrc[base + 16 + lane16];
            float4 ev = *(const float4*)(es + s1 * 4);
            al1.x = lrelu_att(ev.x + edv.x); al1.y = lrelu_att(ev.y + edv.y);
            al1.z = lrelu_att(ev.z + edv.z); al1.w = lrelu_att(ev.w + edv.w);
        }
        float4 mx = make_float4(fmaxf(al0.x, al1.x), fmaxf(al0.y, al1.y),
                                fmaxf(al0.z, al1.z), fmaxf(al0.w, al1.w));
#pragma unroll
        for (int o = 1; o < 16; o <<= 1) {
            mx.x = fmaxf(mx.x, __shfl_xor(mx.x, o));
            mx.y = fmaxf(mx.y, __shfl_xor(mx.y, o));
            mx.z = fmaxf(mx.z, __shfl_xor(mx.z, o));
            mx.w = fmaxf(mx.w, __shfl_xor(mx.w, o));
        }
        float4 ex0 = make_float4(0.f, 0.f, 0.f, 0.f), ex1 = ex0;
        if (lane16 < deg) {
            ex0.x = __expf(al0.x - mx.x); ex0.y = __expf(al0.y - mx.y);
            ex0.z = __expf(al0.z - mx.z); ex0.w = __expf(al0.w - mx.w);
        }
        if (lane16 + 16 < deg) {
            ex1.x = __expf(al1.x - mx.x); ex1.y = __expf(al1.y - mx.y);
            ex1.z = __expf(al1.z - mx.z); ex1.w = __expf(al1.w - mx.w);
        }
        denp.x = ex0.x + ex1.x; denp.y = ex0.y + ex1.y;
        denp.z = ex0.z + ex1.z; denp.w = ex0.w + ex1.w;
        sbuf[grp][lane16] = s0;
        sbuf[grp][lane16 + 16] = s1;
        *(float4*)&exbuf[grp][lane16][0] = ex0;
        *(float4*)&exbuf[grp][lane16 + 16][0] = ex1;
        // wave-coherent LDS within group: no barrier needed
        const int dceil = (deg + 1) & ~1;
#pragma unroll 4
        for (int i = 0; i < dceil; i += 2) {
            int si = sbuf[grp][i + sub];
            float e = exbuf[grp][i + sub][hq8];
            uint4 hv = h16[si * 8 + l8];
            acc8[0] = fmaf(e, bflo(hv.x), acc8[0]);
            acc8[1] = fmaf(e, bfhi(hv.x), acc8[1]);
            acc8[2] = fmaf(e, bflo(hv.y), acc8[2]);
            acc8[3] = fmaf(e, bfhi(hv.y), acc8[3]);
            acc8[4] = fmaf(e, bflo(hv.z), acc8[4]);
            acc8[5] = fmaf(e, bfhi(hv.z), acc8[5]);
            acc8[6] = fmaf(e, bflo(hv.w), acc8[6]);
            acc8[7] = fmaf(e, bfhi(hv.w), acc8[7]);
        }
    } else {
        // ---- slow path: chunked two-pass (deg > 32, rare) ----
        float4 mx = make_float4(-INFINITY, -INFINITY, -INFINITY, -INFINITY);
        for (int c0 = 0; c0 < deg; c0 += 16) {
            if (c0 + lane16 < deg) {
                int s = ssrc[base + c0 + lane16];
                float4 ev = *(const float4*)(es + s * 4);
                mx.x = fmaxf(mx.x, lrelu_att(ev.x + edv.x));
                mx.y = fmaxf(mx.y, lrelu_att(ev.y + edv.y));
                mx.z = fmaxf(mx.z, lrelu_att(ev.z + edv.z));
                mx.w = fmaxf(mx.w, lrelu_att(ev.w + edv.w));
            }
        }
#pragma unroll
        for (int o = 1; o < 16; o <<= 1) {
            mx.x = fmaxf(mx.x, __shfl_xor(mx.x, o));
            mx.y = fmaxf(mx.y, __shfl_xor(mx.y, o));
            mx.z = fmaxf(mx.z, __shfl_xor(mx.z, o));
            mx.w = fmaxf(mx.w, __shfl_xor(mx.w, o));
        }
        for (int c0 = 0; c0 < deg; c0 += 16) {
            int cn = min(16, deg - c0);
            float4 ex = make_float4(0.f, 0.f, 0.f, 0.f);
            int s = 0;
            if (lane16 < cn) {
                s = ssrc[base + c0 + lane16];
                float4 ev = *(const float4*)(es + s * 4);
                ex.x = __expf(lrelu_att(ev.x + edv.x) - mx.x);
                ex.y = __expf(lrelu_att(ev.y + edv.y) - mx.y);
                ex.z = __expf(lrelu_att(ev.z + edv.z) - mx.z);
                ex.w = __expf(lrelu_att(ev.w + edv.w) - mx.w);
            }
            denp.x += ex.x; denp.y += ex.y; denp.z += ex.z; denp.w += ex.w;
            sbuf[grp][lane16] = s;
            *(float4*)&exbuf[grp][lane16][0] = ex;
            const int pc = (cn + 1) & ~1;
            for (int i = 0; i < pc; i += 2) {
                int si = sbuf[grp][i + sub];
                float e = exbuf[grp][i + sub][hq8];
                uint4 hv = h16[si * 8 + l8];
                acc8[0] = fmaf(e, bflo(hv.x), acc8[0]);
                acc8[1] = fmaf(e, bfhi(hv.x), acc8[1]);
                acc8[2] = fmaf(e, bflo(hv.y), acc8[2]);
                acc8[3] = fmaf(e, bfhi(hv.y), acc8[3]);
                acc8[4] = fmaf(e, bflo(hv.z), acc8[4]);
                acc8[5] = fmaf(e, bfhi(hv.z), acc8[5]);
                acc8[6] = fmaf(e, bflo(hv.w), acc8[6]);
                acc8[7] = fmaf(e, bfhi(hv.w), acc8[7]);
            }
        }
    }

    // ---- join: uniform control flow from here ----
    // combine the edge pair (lanes l8 <-> l8+8 within group)
#pragma unroll
    for (int q = 0; q < 8; ++q) acc8[q] += __shfl_xor(acc8[q], 8);
    // den reduce over the 16-lane group
#pragma unroll
    for (int o = 1; o < 16; o <<= 1) {
        denp.x += __shfl_xor(denp.x, o);
        denp.y += __shfl_xor(denp.y, o);
        denp.z += __shfl_xor(denp.z, o);
        denp.w += __shfl_xor(denp.w, o);
    }
    float dh = hq8 == 0 ? denp.x : hq8 == 1 ? denp.y : hq8 == 2 ? denp.z : denp.w;
    float inv = 1.f / (dh + 1e-16f);
    float o8[8];
#pragma unroll
    for (int q = 0; q < 8; ++q) o8[q] = acc8[q] * inv;

    if (sub == 0) {
        *(float4*)(agg + n * 64 + l8 * 8)     = make_float4(o8[0], o8[1], o8[2], o8[3]);
        *(float4*)(agg + n * 64 + l8 * 8 + 4) = make_float4(o8[4], o8[5], o8[6], o8[7]);
    }

    // ---- BN stats: shuffle-reduce across the wave's 4 nodes ----
    float sv[8], qv[8];
#pragma unroll
    for (int q = 0; q < 8; ++q) {
        float v = (sub == 0) ? o8[q] : 0.f;
        sv[q] = v; qv[q] = v * v;
    }
#pragma unroll
    for (int q = 0; q < 8; ++q) {
        sv[q] += __shfl_xor(sv[q], 16); sv[q] += __shfl_xor(sv[q], 32);
        qv[q] += __shfl_xor(qv[q], 16); qv[q] += __shfl_xor(qv[q], 32);
    }
    if ((threadIdx.x & 63) < 8) {
        *(float4*)&stS[wid][l8 * 8]     = make_float4(sv[0], sv[1], sv[2], sv[3]);
        *(float4*)&stS[wid][l8 * 8 + 4] = make_float4(sv[4], sv[5], sv[6], sv[7]);
        *(float4*)&stQ[wid][l8 * 8]     = make_float4(qv[0], qv[1], qv[2], qv[3]);
        *(float4*)&stQ[wid][l8 * 8 + 4] = make_float4(qv[4], qv[5], qv[6], qv[7]);
    }
    __syncthreads();
    if (threadIdx.x < 64) {
        int j = threadIdx.x;
        float ssum = stS[0][j] + stS[1][j] + stS[2][j] + stS[3][j];
        float qsum = stQ[0][j] + stQ[1][j] + stQ[2][j] + stQ[3][j];
        double* rep = bnrep + (size_t)(blockIdx.x & (NREP - 1)) * 128;
        atomicAdd(&rep[j], (double)ssum);
        atomicAdd(&rep[64 + j], (double)qsum);
    }
}

// ---- norm + GraphSizeNorm + LeakyReLU + pool + residual ----
constexpr int NA_BLOCKS = 512;
constexpr int NA_NODES = (NN + NA_BLOCKS - 1) / NA_BLOCKS;   // 196
__global__ __launch_bounds__(256) void k_norm_act(const float* __restrict__ agg,
                                                  const double* __restrict__ bnrep,
                                                  const float* __restrict__ gamma,
                                                  const float* __restrict__ beta,
                                                  const int* __restrict__ batch,
                                                  const float* __restrict__ cnt,
                                                  float* __restrict__ xcur,
                                                  float* __restrict__ pool) {
    __shared__ float sp[GG * 64];
    __shared__ float s_sc[64], s_shf[64];
    for (int i = threadIdx.x; i < GG * 64; i += 256) sp[i] = 0.f;
    if (threadIdx.x < 64) {
        int j = threadIdx.x;
        double s1 = 0.0, s2 = 0.0;
        for (int rp = 0; rp < NREP; ++rp) {
            s1 += bnrep[(size_t)rp * 128 + j];
            s2 += bnrep[(size_t)rp * 128 + 64 + j];
        }
        double mean = s1 / (double)NN;
        double var = s2 / (double)NN - mean * mean;
        float sc = (float)(1.0 / sqrt(var + (double)EPS)) * gamma[j];
        s_sc[j] = sc;
        s_shf[j] = beta[j] - (float)mean * sc;
    }
    __syncthreads();
    const int j = threadIdx.x & 63, r = threadIdx.x >> 6;
    const float sc = s_sc[j], shf = s_shf[j];
    const int n0 = blockIdx.x * NA_NODES;
    const int n1 = min(n0 + NA_NODES, NN);
    float racc = 0.f;
    int curg = -1;
    float rinv = 0.f;
    for (int n = n0 + r; n < n1; n += 4) {
        int g = batch[n];
        if (g != curg) {
            if (curg >= 0) atomicAdd(&sp[curg * 64 + j], racc);
            curg = g; racc = 0.f;
            rinv = rsqrtf(cnt[g]);
        }
        float v = (agg[n * 64 + j] * sc + shf) * rinv;
        v = v > 0.f ? v : SLOPE_ACT * v;
        racc += v;
        xcur[n * 64 + j] += v;
    }
    if (curg >= 0) atomicAdd(&sp[curg * 64 + j], racc);
    __syncthreads();
    for (int i = threadIdx.x; i < GG * 64; i += 256)
        if (sp[i] != 0.f) atomicAdd(&pool[i], sp[i]);
}

// ---- readout head ----
__global__ void k_head(const float* __restrict__ pools,
                       const float* __restrict__ cnt,
                       const float* __restrict__ Wr,
                       const float* __restrict__ br,
                       float* __restrict__ out) {
    __shared__ float risk[GG * NCLS];
    int t = threadIdx.x;
    if (t < GG * NCLS) {
        int g = t / NCLS, c = t % NCLS;
        float acc = br[c];
        float icnt = 1.f / cnt[g];
        for (int k = 0; k < (LL + 1) * DIM; ++k) {
            int l = k >> 6, j = k & 63;
            float xc = pools[(l * GG + g) * 64 + j] * icnt;
            acc += xc * Wr[k * NCLS + c];
        }
        risk[t] = acc;
        out[t] = acc;
    }
    __syncthreads();
    if (t < GG) {
        float r0 = risk[t * 2], r1 = risk[t * 2 + 1];
        float m = fmaxf(r0, r1);
        float e0 = expf(r0 - m), e1 = expf(r1 - m);
        float s = e0 + e1;
        out[GG * NCLS + t * 2] = e0 / s;
        out[GG * NCLS + t * 2 + 1] = e1 / s;
        out[2 * GG * NCLS + t] = (r1 > r0) ? 1.f : 0.f;
    }
}

extern "C" void kernel_launch(void* const* d_in, const int* in_sizes, int n_in,
                              void* d_out, int out_size, void* d_ws, size_t ws_size,
                              hipStream_t stream) {
    const float* x     = (const float*)d_in[0];
    const int*   ei    = (const int*)d_in[1];
    const int*   batch = (const int*)d_in[2];
    const float* W     = (const float*)d_in[4];
    const float* asrc  = (const float*)d_in[5];
    const float* adst  = (const float*)d_in[6];
    const float* gamma = (const float*)d_in[8];
    const float* beta  = (const float*)d_in[9];
    const float* Wr    = (const float*)d_in[10];
    const float* br    = (const float*)d_in[11];
    float* out = (float*)d_out;

    char* ws = (char*)d_ws;
    size_t off = 0;
    auto alloc = [&](size_t bytes) {
        void* p = ws + off;
        off += (bytes + 255) & ~(size_t)255;
        return p;
    };
    float*          xcur      = (float*)alloc((size_t)NN * 64 * 4);
    unsigned short* h         = (unsigned short*)alloc((size_t)NN * 64 * 2);
    float*          agg       = (float*)alloc((size_t)NN * 64 * 4);
    float*          es        = (float*)alloc((size_t)NN * 4 * 4);
    float*          ed        = (float*)alloc((size_t)NN * 4 * 4);
    int*            row_start = (int*)alloc((size_t)(NN + 1) * 4);
    int*            ssrc      = (int*)alloc((size_t)EE * 4);
    double*         bnrep     = (double*)alloc((size_t)NREP * 128 * 8);
    float*          pools     = (float*)alloc((size_t)(LL + 1) * GG * 64 * 4);
    float*          cnt       = (float*)alloc((size_t)GG * 4);
    (void)ws_size; (void)in_sizes; (void)n_in; (void)out_size;

    // CSR-build scratch aliases agg (dead until k_gat_agg overwrites it)
    int* deg     = (int*)agg;
    int* cursor  = (int*)agg + NN;
    int* bsum    = (int*)agg + 2 * NN;
    int* bsum_sc = (int*)agg + 2 * NN + 256;

    hipMemsetAsync(pools, 0, (size_t)(LL + 1) * GG * 64 * 4, stream);
    hipMemsetAsync(cnt, 0, (size_t)GG * 4, stream);
    hipMemsetAsync(deg, 0, (size_t)NN * 4, stream);

    // ---- build CSR (once; reused by all 3 layers) ----
    k_hist<<<(EE / 4 + 255) / 256, 256, 0, stream>>>(ei, deg);
    k_scan1<<<NSCAN, 256, 0, stream>>>(deg, row_start, bsum);
    k_scan2<<<1, 128, 0, stream>>>(bsum, bsum_sc);
    k_scan3<<<(NN + 255) / 256, 256, 0, stream>>>(row_start, bsum_sc, cursor);
    k_fill<<<8 * FILL_NBLK, 256, 0, stream>>>(ei, cursor, ssrc);

    k_pool0<<<2048, 256, 0, stream>>>(x, batch, pools, cnt, xcur);

    for (int l = 0; l < LL; ++l) {
        k_gemm<<<(NN + 63) / 64, 256, 0, stream>>>(xcur, W + l * DIM * DIM,
                                                   asrc + l * HH * CC, adst + l * HH * CC,
                                                   h, es, ed, bnrep);
        k_gat_agg<<<NN / 16, 256, 0, stream>>>(row_start, ssrc, es, ed, h, agg, bnrep);
        k_norm_act<<<NA_BLOCKS, 256, 0, stream>>>(agg, bnrep, gamma + l * DIM,
                                                  beta + l * DIM, batch, cnt,
                                                  xcur, pools + (size_t)(l + 1) * GG * 64);
    }

    k_head<<<1, 64, 0, stream>>>(pools, cnt, Wr, br, out);
}